// Round 5
// baseline (473.378 us; speedup 1.0000x reference)
//
#include <hip/hip_runtime.h>
#include <cstdint>
#include <cstddef>

// ---------------------------------------------------------------------------
// 4-layer GCN. Round 15: fused gather+GEMM with restored occupancy.
// Round-14 post-mortem: 128-row tiles -> 391 blocks -> 1.5 blocks/CU -> the
// latency-bound gather phase ran at ~12 waves/CU (27% occ) and fusion lost.
// Now 64-row tiles (32 KB LDS), 512 threads, grid=782 (~3 blocks/CU, ~24
// waves/CU); GEMM phase = 8 waves x (32x64) sub-tiles, acc[2][4].
// ---------------------------------------------------------------------------

typedef __bf16 bf16x8 __attribute__((ext_vector_type(8)));
typedef float f32x4 __attribute__((ext_vector_type(4)));

__device__ __forceinline__ unsigned short f2bf(float v) {   // RNE
    union { float f; unsigned u; } x; x.f = v;
    unsigned r = x.u + 0x7fff + ((x.u >> 16) & 1);
    return (unsigned short)(r >> 16);
}
__device__ __forceinline__ float bf2f(unsigned short h) {
    union { unsigned u; float f; } x; x.u = (unsigned)h << 16; return x.f;
}

// async global->LDS, 16B per lane; lds base must be wave-uniform
__device__ __forceinline__ void gl2lds16(const void* g, void* l) {
    __builtin_amdgcn_global_load_lds(
        (const __attribute__((address_space(1))) unsigned int*)g,
        (__attribute__((address_space(3))) unsigned int*)l, 16, 0, 0);
}

// acc[0..3] += bf16x4(v) * n
__device__ __forceinline__ void fma4(const uint2 v, float n, float* acc) {
    acc[0] += bf2f((unsigned short)(v.x & 0xffff)) * n;
    acc[1] += bf2f((unsigned short)(v.x >> 16)) * n;
    acc[2] += bf2f((unsigned short)(v.y & 0xffff)) * n;
    acc[3] += bf2f((unsigned short)(v.y >> 16)) * n;
}

// ---------------- edge-index dtype detection -------------------------------
__global__ void k_flag_init(int* flag) {
    if (blockIdx.x == 0 && threadIdx.x == 0) *flag = 1;
}

__global__ void k_flag_check(const long long* __restrict__ p, int E, long long N,
                             int* flag) {
    long long i = (long long)blockIdx.x * blockDim.x + threadIdx.x;
    long long stride = (long long)gridDim.x * blockDim.x;
    for (; i < E; i += stride) {
        long long v = p[i];
        if (v < 0 || v >= N) *flag = 0;
    }
}

__device__ __forceinline__ void load_edge(const void* eidx, int fl, int E, int i,
                                          int& s, int& d) {
    if (fl) {
        s = (int)((const long long*)eidx)[i];
        d = (int)((const long long*)eidx)[E + i];
    } else {
        s = ((const int*)eidx)[i];
        d = ((const int*)eidx)[E + i];
    }
}

// ---------------- CSR build -------------------------------------------------
__global__ void k_zero_i32(int* __restrict__ p, int n) {
    int i = blockIdx.x * blockDim.x + threadIdx.x;
    if (i < n) p[i] = 0;
}

__global__ void k_count(const void* __restrict__ eidx, const int* __restrict__ flag,
                        int* __restrict__ counts, int E) {
    int i = blockIdx.x * blockDim.x + threadIdx.x;
    if (i >= E) return;
    int s, d;
    load_edge(eidx, *flag, E, i, s, d);
    atomicAdd(&counts[d], 1);
}

__global__ void k_dinv(const int* __restrict__ counts, float* __restrict__ dinv,
                       int N) {
    int i = blockIdx.x * blockDim.x + threadIdx.x;
    if (i < N) dinv[i] = rsqrtf((float)counts[i] + 1.0f);
}

// per-1024-chunk sums (256 threads, 4 elems/thread)
__global__ __launch_bounds__(256) void k_bsum(const int* __restrict__ counts,
                                              int* __restrict__ bsum, int N) {
    __shared__ int ws[4];
    int tid = threadIdx.x, lane = tid & 63, wid = tid >> 6;
    int base = blockIdx.x * 1024 + tid * 4;
    int s = 0;
    if (base + 3 < N) {
        int4 v = *(const int4*)&counts[base];
        s = v.x + v.y + v.z + v.w;
    } else {
#pragma unroll
        for (int t = 0; t < 4; t++) {
            int i = base + t;
            if (i < N) s += counts[i];
        }
    }
#pragma unroll
    for (int off = 32; off > 0; off >>= 1) s += __shfl_xor(s, off);
    if (lane == 0) ws[wid] = s;
    __syncthreads();
    if (tid == 0) bsum[blockIdx.x] = ws[0] + ws[1] + ws[2] + ws[3];
}

// small single-block exclusive scan (block sums; n is small)
__global__ __launch_bounds__(1024) void k_scan(const int* __restrict__ counts,
                                               int* __restrict__ starts, int N) {
    __shared__ int wsum[16];
    __shared__ int wscan[16];
    __shared__ int s_carry;
    int tid = threadIdx.x;
    int lane = tid & 63, wid = tid >> 6;
    if (tid == 0) s_carry = 0;
    __syncthreads();
    for (int base = 0; base < N; base += 1024) {
        int i = base + tid;
        int v = (i < N) ? counts[i] : 0;
        int incl = v;
#pragma unroll
        for (int off = 1; off < 64; off <<= 1) {
            int t = __shfl_up(incl, off);
            if (lane >= off) incl += t;
        }
        if (lane == 63) wsum[wid] = incl;
        __syncthreads();
        if (wid == 0 && lane < 16) {
            int w = wsum[lane];
#pragma unroll
            for (int off = 1; off < 16; off <<= 1) {
                int t = __shfl_up(w, off);
                if (lane >= off) w += t;
            }
            wscan[lane] = w;
        }
        __syncthreads();
        int woff = (wid > 0) ? wscan[wid - 1] : 0;
        int excl = s_carry + woff + incl - v;
        if (i < N) starts[i] = excl;
        int total = wscan[15];
        __syncthreads();
        if (tid == 0) s_carry += total;
        __syncthreads();
    }
    if (tid == 0) starts[N] = s_carry;
}

// final: per-1024-chunk exclusive scan + block offset
__global__ __launch_bounds__(256) void k_scan_final(
        const int* __restrict__ counts, const int* __restrict__ boffs,
        int* __restrict__ starts, int N) {
    __shared__ int ws[4];
    int tid = threadIdx.x, lane = tid & 63, wid = tid >> 6;
    int base = blockIdx.x * 1024 + tid * 4;
    int v[4];
#pragma unroll
    for (int t = 0; t < 4; t++) {
        int i = base + t;
        v[t] = (i < N) ? counts[i] : 0;
    }
    int tsum = v[0] + v[1] + v[2] + v[3];
    int incl = tsum;
#pragma unroll
    for (int off = 1; off < 64; off <<= 1) {
        int t = __shfl_up(incl, off);
        if (lane >= off) incl += t;
    }
    if (lane == 63) ws[wid] = incl;
    __syncthreads();
    int woff = 0;
#pragma unroll
    for (int w = 0; w < 4; w++)
        if (w < wid) woff += ws[w];
    int run = boffs[blockIdx.x] + woff + incl - tsum;
#pragma unroll
    for (int t = 0; t < 4; t++) {
        int i = base + t;
        if (i < N) starts[i] = run;
        run += v[t];
    }
    if (blockIdx.x == 0 && tid == 0) starts[N] = boffs[gridDim.x];
}

__global__ void k_copy_i32(const int* __restrict__ a, int* __restrict__ b, int n) {
    int i = blockIdx.x * blockDim.x + threadIdx.x;
    if (i < n) b[i] = a[i];
}

// fill CSR; also precompute per-edge norm = dinv[src]
__global__ void k_fill(const void* __restrict__ eidx, const int* __restrict__ flag,
                       int* __restrict__ cursor, int* __restrict__ srcs,
                       float* __restrict__ nrm, const float* __restrict__ dinv,
                       int E) {
    int i = blockIdx.x * blockDim.x + threadIdx.x;
    if (i >= E) return;
    int s, d;
    load_edge(eidx, *flag, E, i, s, d);
    int pos = atomicAdd(&cursor[d], 1);
    srcs[pos] = s;
    nrm[pos] = dinv[s];
}

// ---------------- conversions ----------------------------------------------
__global__ void k_cvt_x(const float* __restrict__ x, unsigned short* __restrict__ o,
                        long long n4) {
    long long i = (long long)blockIdx.x * blockDim.x + threadIdx.x;
    long long stride = (long long)gridDim.x * blockDim.x;
    for (; i < n4; i += stride) {
        float4 v = ((const float4*)x)[i];
        unsigned a = (unsigned)f2bf(v.x) | ((unsigned)f2bf(v.y) << 16);
        unsigned b = (unsigned)f2bf(v.z) | ((unsigned)f2bf(v.w) << 16);
        ((uint2*)o)[i] = make_uint2(a, b);
    }
}

// W [K][H] fp32 -> transposed, padded [256][256] plain bf16 (zeros outside)
__global__ void k_cvt_w(const float* __restrict__ W, unsigned short* __restrict__ T,
                        int K, int H) {
    int idx = blockIdx.x * blockDim.x + threadIdx.x;
    if (idx >= 256 * 256) return;
    int k = idx & 255, n = idx >> 8;
    float v = (k < K && n < H) ? W[k * H + n] : 0.0f;
    T[n * 256 + k] = f2bf(v);
}

// ---------------- single-pass bf16 MFMA GEMM (layer 1) ---------------------
// C[M][256] = A[M][256] @ W[256][256]; A plain bf16, W transposed bf16.
// 128x128 tile, 4 waves, 4x4 grid of 16x16x32 MFMA; XCD-chunked 1-D grid.
__global__ __launch_bounds__(256) void k_gemm_mfma(
        const unsigned short* __restrict__ A,
        const unsigned short* __restrict__ BT,
        unsigned short* __restrict__ C, int M) {
    __shared__ unsigned short ldsA[4 * 128 * 8];    // chunk c = kq*128+m
    __shared__ unsigned short ldsB[4 * 128 * 8];    // chunk c = kq*128+n

    // xcd-chunked bijective remap
    int g = blockIdx.x, nwg = gridDim.x;
    int q = nwg >> 3, r = nwg & 7;
    int xcd = g & 7, slot = g >> 3;
    int work = (xcd < r) ? xcd * (q + 1) + slot
                         : r * (q + 1) + (xcd - r) * q + slot;
    int col0 = (work & 1) * 128;
    int row0 = (work >> 1) * 128;

    int tid = threadIdx.x;
    int lane = tid & 63;
    int w = tid >> 6;
    int wm = (w & 1) * 64, wn = (w >> 1) * 64;
    int kq = lane >> 4, lr = lane & 15;

    f32x4 acc[4][4] = {};

    for (int k0 = 0; k0 < 256; k0 += 32) {
        __syncthreads();
#pragma unroll
        for (int i = 0; i < 2; i++) {
            int c = (i * 4 + w) * 64 + lane;
            int m = c & 127, kqq = c >> 7;
            int row = row0 + m; if (row >= M) row = M - 1;   // clamp: valid addr
            gl2lds16(&A[(long long)row * 256 + k0 + kqq * 8],
                     &ldsA[(i * 4 + w) * 512]);
        }
#pragma unroll
        for (int i = 0; i < 2; i++) {
            int c = (i * 4 + w) * 64 + lane;
            int n = c & 127, kqq = c >> 7;
            gl2lds16(&BT[(long long)(col0 + n) * 256 + k0 + kqq * 8],
                     &ldsB[(i * 4 + w) * 512]);
        }
        __syncthreads();

        bf16x8 a[4], b[4];
#pragma unroll
        for (int t = 0; t < 4; t++) {
            int m = wm + t * 16 + lr;
            a[t] = *(const bf16x8*)&ldsA[(kq * 128 + m) * 8];
            int n = wn + t * 16 + lr;
            b[t] = *(const bf16x8*)&ldsB[(kq * 128 + n) * 8];
        }
#pragma unroll
        for (int mt = 0; mt < 4; mt++)
#pragma unroll
            for (int nt = 0; nt < 4; nt++)
                acc[mt][nt] = __builtin_amdgcn_mfma_f32_16x16x32_bf16(
                    a[mt], b[nt], acc[mt][nt], 0, 0, 0);
    }

    // epilogue: C/D layout col=lane&15, row=(lane>>4)*4+reg  [m89-verified]
#pragma unroll
    for (int mt = 0; mt < 4; mt++) {
#pragma unroll
        for (int nt = 0; nt < 4; nt++) {
            int col = col0 + wn + nt * 16 + lr;
            int rowb = row0 + wm + mt * 16 + kq * 4;
#pragma unroll
            for (int r2 = 0; r2 < 4; r2++) {
                int row = rowb + r2;
                if (row < M) C[(long long)row * 256 + col] = f2bf(acc[mt][nt][r2]);
            }
        }
    }
}

// ---------------- wave-per-dst CSR aggregation core ------------------------
// 64 lanes = 1 dst row; 4 features/lane (uint2); 8-deep independent batch.
__device__ __forceinline__ void agg_rows(
        const unsigned short* __restrict__ h,
        const int* __restrict__ srcs, const float* __restrict__ nrm,
        const int* __restrict__ starts, int d, int f0, float dd, float* acc) {
    int lane = threadIdx.x & 63;
    int e0 = starts[d], e1 = starts[d + 1];
    int cnt = e1 - e0;
    int cpre = cnt < 64 ? cnt : 64;

    acc[0] = acc[1] = acc[2] = acc[3] = 0.0f;
    {   // self-loop (also warms L1 with row d for masked slots)
        uint2 v = *(const uint2*)&h[((long long)d << 8) + f0];
        fma4(v, dd, acc);
    }
    int sv = 0; float nv = 0.0f;
    if (lane < cpre) { sv = srcs[e0 + lane]; nv = nrm[e0 + lane]; }

    for (int base = 0; base < cpre; base += 8) {
        uint2 vv[8]; float nn[8];
#pragma unroll
        for (int t = 0; t < 8; t++) {
            int j = base + t;                    // <= 63 always
            int s = __shfl(sv, j);
            float n = __shfl(nv, j);
            if (j >= cpre) { s = d; n = 0.0f; }  // wave-uniform mask
            nn[t] = n;
            vv[t] = *(const uint2*)&h[((long long)s << 8) + f0];
        }
#pragma unroll
        for (int t = 0; t < 8; t++) fma4(vv[t], nn[t], acc);
    }
    for (int e = e0 + 64; e < e1; e++) {         // rare: degree > 64
        int s0 = srcs[e];
        float n0 = nrm[e];
        uint2 v0 = *(const uint2*)&h[((long long)s0 << 8) + f0];
        fma4(v0, n0, acc);
    }
}

// ---------------- fused gather + GEMM (middle layers) ----------------------
// Block = 64 dst rows, 512 threads (8 waves). Static LDS = 32 KB.
// Phase 1: each wave aggregates 8 rows (relu+bias) into XOR-swizzled LDS
//          A-tile [64][256] bf16 (byte ^= (row&7)<<4).
// Phase 2: single __syncthreads, then barrier-free 64x256 GEMM; 8 waves in
//          2x4 grid of 32x64 sub-tiles (acc[2][4]); A-frags from LDS,
//          B-frags read directly from L2-resident BT (128 KB).
__global__ __launch_bounds__(512, 6) void k_fused(
        const unsigned short* __restrict__ h,   // prev layer C, bf16 [N][256]
        const int* __restrict__ srcs, const float* __restrict__ nrm,
        const int* __restrict__ starts, const float* __restrict__ dinv,
        const float* __restrict__ bias,         // gather-layer bias
        const unsigned short* __restrict__ BT,  // next-layer W^T [256][256]
        unsigned short* __restrict__ C,         // out, bf16 [N][256]
        int N, int H) {
    __shared__ unsigned short ldsA[64 * 256];       // 32 KB, swizzled rows

    int tid = threadIdx.x;
    int lane = tid & 63;
    int w = tid >> 6;                                // 0..7
    int row0 = blockIdx.x * 64;

    // ---- phase 1: gather 8 rows per wave ----
    int f0 = lane * 4;
    for (int i = 0; i < 8; i++) {
        int dl = w * 8 + i;
        int d = row0 + dl;
        if (d < N) {
            float dd = dinv[d];
            float acc[4];
            agg_rows(h, srcs, nrm, starts, d, f0, dd, acc);
            unsigned short o[4];
#pragma unroll
            for (int t = 0; t < 4; t++) {
                int f = f0 + t;
                float bb = (f < H) ? bias[f] : 0.0f;
                float v = fmaxf(acc[t] * dd + bb, 0.0f);  // relu; pads stay 0
                o[t] = f2bf(v);
            }
            unsigned o01 = (unsigned)o[0] | ((unsigned)o[1] << 16);
            unsigned o23 = (unsigned)o[2] | ((unsigned)o[3] << 16);
            unsigned boff = (unsigned)(dl * 512 + lane * 8) ^
                            (((unsigned)dl & 7u) << 4);
            *(uint2*)((char*)ldsA + boff) = make_uint2(o01, o23);
        }
    }
    __syncthreads();

    // ---- phase 2: GEMM 64x256, no barriers ----
    int wm = (w & 1) * 32, wn = (w >> 1) * 64;
    int kq = lane >> 4, lr = lane & 15;
    f32x4 acc[2][4] = {};

#pragma unroll
    for (int k0 = 0; k0 < 256; k0 += 32) {
        bf16x8 a[2], b[4];
#pragma unroll
        for (int t = 0; t < 2; t++) {
            int row = wm + t * 16 + lr;
            unsigned boff = (unsigned)(row * 512 + k0 * 2 + kq * 16) ^
                            (((unsigned)row & 7u) << 4);
            a[t] = *(const bf16x8*)((const char*)ldsA + boff);
        }
#pragma unroll
        for (int t = 0; t < 4; t++) {
            int n = wn + t * 16 + lr;
            b[t] = *(const bf16x8*)&BT[(long long)n * 256 + k0 + kq * 8];
        }
#pragma unroll
        for (int mt = 0; mt < 2; mt++)
#pragma unroll
            for (int nt = 0; nt < 4; nt++)
                acc[mt][nt] = __builtin_amdgcn_mfma_f32_16x16x32_bf16(
                    a[mt], b[nt], acc[mt][nt], 0, 0, 0);
    }

    // epilogue: C/D layout col=lane&15, row=(lane>>4)*4+reg
#pragma unroll
    for (int mt = 0; mt < 2; mt++) {
#pragma unroll
        for (int nt = 0; nt < 4; nt++) {
            int col = wn + nt * 16 + lr;
            int rowb = row0 + wm + mt * 16 + kq * 4;
#pragma unroll
            for (int r2 = 0; r2 < 4; r2++) {
                int row = rowb + r2;
                if (row < N) C[(long long)row * 256 + col] = f2bf(acc[mt][nt][r2]);
            }
        }
    }
}

// ---------------- layer-4: gather + fused log_softmax ----------------------
__global__ __launch_bounds__(256) void k_gather_lsm(
        const unsigned short* __restrict__ h,   // bf16 [N][256]
        const int* __restrict__ srcs, const float* __restrict__ nrm,
        const int* __restrict__ starts,
        const float* __restrict__ dinv, const float* __restrict__ bias,
        float* __restrict__ out, int N, int H) {
    int d = blockIdx.x * 4 + (threadIdx.x >> 6);
    if (d >= N) return;
    int lane = threadIdx.x & 63;
    int f0 = lane * 4;
    float dd = dinv[d];

    float acc[4];
    agg_rows(h, srcs, nrm, starts, d, f0, dd, acc);

    float v[4];
    float m = -INFINITY;
#pragma unroll
    for (int t = 0; t < 4; t++) {
        int f = f0 + t;
        float bb = (f < H) ? bias[f] : 0.0f;
        v[t] = acc[t] * dd + bb;
        if (f < H) m = fmaxf(m, v[t]);
    }
#pragma unroll
    for (int off = 32; off > 0; off >>= 1) m = fmaxf(m, __shfl_xor(m, off));
    float s = 0.0f;
#pragma unroll
    for (int t = 0; t < 4; t++) {
        int f = f0 + t;
        if (f < H) s += __expf(v[t] - m);
    }
#pragma unroll
    for (int off = 32; off > 0; off >>= 1) s += __shfl_xor(s, off);
    float lse = m + logf(s);
#pragma unroll
    for (int t = 0; t < 4; t++) {
        int f = f0 + t;
        if (f < H) out[(long long)d * H + f] = v[t] - lse;
    }
}

// ---------------------------------------------------------------------------
extern "C" void kernel_launch(void* const* d_in, const int* in_sizes, int n_in,
                              void* d_out, int out_size, void* d_ws, size_t ws_size,
                              hipStream_t stream) {
    const float* x    = (const float*)d_in[0];
    const void*  eidx = d_in[1];
    const float* W[4] = {(const float*)d_in[2], (const float*)d_in[4],
                         (const float*)d_in[6], (const float*)d_in[8]};
    const float* b[4] = {(const float*)d_in[3], (const float*)d_in[5],
                         (const float*)d_in[7], (const float*)d_in[9]};

    const int H   = in_sizes[3];          // 246
    const int E   = in_sizes[1] / 2;      // 320000
    const int FIN = in_sizes[2] / H;      // 256
    const int N   = in_sizes[0] / FIN;    // 50000

    auto align = [](size_t v) { return (v + 255) / 256 * 256; };
    char* ws = (char*)d_ws;
    size_t off = 0;
    int* flag = (int*)(ws + off);             off += 256;
    float* dinv = (float*)(ws + off);         off += align((size_t)N * 4);
    int* counts = (int*)(ws + off);           off += align((size_t)N * 4);
    int* starts = (int*)(ws + off);           off += align((size_t)(N + 1) * 4);
    int* srcs = (int*)(ws + off);             off += align((size_t)E * 4);
    float* nrm = (float*)(ws + off);          off += align((size_t)E * 4);
    int nb2 = (N + 1023) / 1024;
    int* bsum = (int*)(ws + off);             off += align((size_t)(nb2 + 1) * 4);
    int* boffs = (int*)(ws + off);            off += align((size_t)(nb2 + 1) * 4);
    unsigned short* Wt[4];
    for (int l = 0; l < 4; l++) {
        Wt[l] = (unsigned short*)(ws + off);  off += 256 * 256 * 2;
    }
    size_t actB = align((size_t)N * 256 * 2);
    unsigned short* A0  = (unsigned short*)(ws + off);  off += actB;
    unsigned short* Cb0 = (unsigned short*)(ws + off);  off += actB;
    unsigned short* Cb1 = (unsigned short*)(ws + off);  off += actB;

    int nb = (N + 255) / 256, eb = (E + 255) / 256;

    // --- edge dtype detection ---
    k_flag_init<<<1, 64, 0, stream>>>(flag);
    k_flag_check<<<512, 256, 0, stream>>>((const long long*)eidx, E, (long long)N, flag);

    // --- CSR build ---
    k_zero_i32<<<nb, 256, 0, stream>>>(counts, N);
    k_count<<<eb, 256, 0, stream>>>(eidx, flag, counts, E);
    k_dinv<<<nb, 256, 0, stream>>>(counts, dinv, N);
    k_bsum<<<nb2, 256, 0, stream>>>(counts, bsum, N);
    k_scan<<<1, 1024, 0, stream>>>(bsum, boffs, nb2);
    k_scan_final<<<nb2, 256, 0, stream>>>(counts, boffs, starts, N);
    k_copy_i32<<<nb, 256, 0, stream>>>(starts, counts, N);
    k_fill<<<eb, 256, 0, stream>>>(eidx, flag, counts, srcs, nrm, dinv, E);

    // --- weight + input conversion ---
    k_cvt_w<<<256, 256, 0, stream>>>(W[0], Wt[0], FIN, H);
    for (int l = 1; l < 4; l++)
        k_cvt_w<<<256, 256, 0, stream>>>(W[l], Wt[l], H, H);
    k_cvt_x<<<1024, 256, 0, stream>>>(x, A0, (long long)N * FIN / 4);

    int ggrid = 2 * ((N + 127) / 128);
    int fgrid = (N + 63) / 64;
    int gb = (N + 3) / 4;

    // --- layer 1: GEMM only ---
    k_gemm_mfma<<<ggrid, 256, 0, stream>>>(A0, Wt[0], Cb0, N);
    // --- fused: gather(l1)+GEMM(l2), gather(l2)+GEMM(l3), gather(l3)+GEMM(l4)
    k_fused<<<fgrid, 512, 0, stream>>>(Cb0, srcs, nrm, starts, dinv, b[0],
                                       Wt[1], Cb1, N, H);
    k_fused<<<fgrid, 512, 0, stream>>>(Cb1, srcs, nrm, starts, dinv, b[1],
                                       Wt[2], Cb0, N, H);
    k_fused<<<fgrid, 512, 0, stream>>>(Cb0, srcs, nrm, starts, dinv, b[2],
                                       Wt[3], Cb1, N, H);
    // --- layer 4 aggregation + log_softmax ---
    k_gather_lsm<<<gb, 256, 0, stream>>>(Cb1, srcs, nrm, starts, dinv, b[3],
                                         (float*)d_out, N, H);
}

// Round 6
// 462.178 us; speedup vs baseline: 1.0242x; 1.0242x over previous
//
#include <hip/hip_runtime.h>
#include <cstdint>
#include <cstddef>

// ---------------------------------------------------------------------------
// 4-layer GCN. Round 16: r15 geometry (64-row tiles, grid 782, 32 KB LDS)
// with r14's register freedom restored: __launch_bounds__(512,4) -> VGPR ~64,
// 8-deep gather batch stays in registers (r15's (512,6) forced VGPR 36 and
// serialized the batch: 83us). Also merged 6 preproc micro-kernels away
// (zero->flag_check, dinv+bsum, copy->scan_final, cvt_w x4 batched).
// ---------------------------------------------------------------------------

typedef __bf16 bf16x8 __attribute__((ext_vector_type(8)));
typedef float f32x4 __attribute__((ext_vector_type(4)));

__device__ __forceinline__ unsigned short f2bf(float v) {   // RNE
    union { float f; unsigned u; } x; x.f = v;
    unsigned r = x.u + 0x7fff + ((x.u >> 16) & 1);
    return (unsigned short)(r >> 16);
}
__device__ __forceinline__ float bf2f(unsigned short h) {
    union { unsigned u; float f; } x; x.u = (unsigned)h << 16; return x.f;
}

// async global->LDS, 16B per lane; lds base must be wave-uniform
__device__ __forceinline__ void gl2lds16(const void* g, void* l) {
    __builtin_amdgcn_global_load_lds(
        (const __attribute__((address_space(1))) unsigned int*)g,
        (__attribute__((address_space(3))) unsigned int*)l, 16, 0, 0);
}

// acc[0..3] += bf16x4(v) * n
__device__ __forceinline__ void fma4(const uint2 v, float n, float* acc) {
    acc[0] += bf2f((unsigned short)(v.x & 0xffff)) * n;
    acc[1] += bf2f((unsigned short)(v.x >> 16)) * n;
    acc[2] += bf2f((unsigned short)(v.y & 0xffff)) * n;
    acc[3] += bf2f((unsigned short)(v.y >> 16)) * n;
}

// ---------------- edge-index dtype detection + counts zero -----------------
__global__ void k_flag_init(int* flag) {
    if (blockIdx.x == 0 && threadIdx.x == 0) *flag = 1;
}

__global__ void k_flag_check(const long long* __restrict__ p, int E, long long N,
                             int* flag, int* __restrict__ counts, int Ncnt) {
    long long i = (long long)blockIdx.x * blockDim.x + threadIdx.x;
    long long stride = (long long)gridDim.x * blockDim.x;
    for (long long j = i; j < Ncnt; j += stride) counts[j] = 0;   // fused zero
    for (; i < E; i += stride) {
        long long v = p[i];
        if (v < 0 || v >= N) *flag = 0;
    }
}

__device__ __forceinline__ void load_edge(const void* eidx, int fl, int E, int i,
                                          int& s, int& d) {
    if (fl) {
        s = (int)((const long long*)eidx)[i];
        d = (int)((const long long*)eidx)[E + i];
    } else {
        s = ((const int*)eidx)[i];
        d = ((const int*)eidx)[E + i];
    }
}

// ---------------- CSR build -------------------------------------------------
__global__ void k_count(const void* __restrict__ eidx, const int* __restrict__ flag,
                        int* __restrict__ counts, int E) {
    int i = blockIdx.x * blockDim.x + threadIdx.x;
    if (i >= E) return;
    int s, d;
    load_edge(eidx, *flag, E, i, s, d);
    atomicAdd(&counts[d], 1);
}

// dinv + per-1024-chunk sums, merged (256 threads, 4 elems/thread)
__global__ __launch_bounds__(256) void k_dinv_bsum(
        const int* __restrict__ counts, float* __restrict__ dinv,
        int* __restrict__ bsum, int N) {
    __shared__ int ws[4];
    int tid = threadIdx.x, lane = tid & 63, wid = tid >> 6;
    int base = blockIdx.x * 1024 + tid * 4;
    int v[4];
#pragma unroll
    for (int t = 0; t < 4; t++) {
        int i = base + t;
        v[t] = (i < N) ? counts[i] : 0;
        if (i < N) dinv[i] = rsqrtf((float)v[t] + 1.0f);
    }
    int s = v[0] + v[1] + v[2] + v[3];
#pragma unroll
    for (int off = 32; off > 0; off >>= 1) s += __shfl_xor(s, off);
    if (lane == 0) ws[wid] = s;
    __syncthreads();
    if (tid == 0) bsum[blockIdx.x] = ws[0] + ws[1] + ws[2] + ws[3];
}

// small single-block exclusive scan (block sums; n is small)
__global__ __launch_bounds__(1024) void k_scan(const int* __restrict__ counts,
                                               int* __restrict__ starts, int N) {
    __shared__ int wsum[16];
    __shared__ int wscan[16];
    __shared__ int s_carry;
    int tid = threadIdx.x;
    int lane = tid & 63, wid = tid >> 6;
    if (tid == 0) s_carry = 0;
    __syncthreads();
    for (int base = 0; base < N; base += 1024) {
        int i = base + tid;
        int v = (i < N) ? counts[i] : 0;
        int incl = v;
#pragma unroll
        for (int off = 1; off < 64; off <<= 1) {
            int t = __shfl_up(incl, off);
            if (lane >= off) incl += t;
        }
        if (lane == 63) wsum[wid] = incl;
        __syncthreads();
        if (wid == 0 && lane < 16) {
            int w = wsum[lane];
#pragma unroll
            for (int off = 1; off < 16; off <<= 1) {
                int t = __shfl_up(w, off);
                if (lane >= off) w += t;
            }
            wscan[lane] = w;
        }
        __syncthreads();
        int woff = (wid > 0) ? wscan[wid - 1] : 0;
        int excl = s_carry + woff + incl - v;
        if (i < N) starts[i] = excl;
        int total = wscan[15];
        __syncthreads();
        if (tid == 0) s_carry += total;
        __syncthreads();
    }
    if (tid == 0) starts[N] = s_carry;
}

// final: per-1024-chunk exclusive scan + block offset; also writes cursor copy
__global__ __launch_bounds__(256) void k_scan_final(
        int* __restrict__ counts, const int* __restrict__ boffs,
        int* __restrict__ starts, int N) {
    __shared__ int ws[4];
    int tid = threadIdx.x, lane = tid & 63, wid = tid >> 6;
    int base = blockIdx.x * 1024 + tid * 4;
    int v[4];
#pragma unroll
    for (int t = 0; t < 4; t++) {
        int i = base + t;
        v[t] = (i < N) ? counts[i] : 0;
    }
    int tsum = v[0] + v[1] + v[2] + v[3];
    int incl = tsum;
#pragma unroll
    for (int off = 1; off < 64; off <<= 1) {
        int t = __shfl_up(incl, off);
        if (lane >= off) incl += t;
    }
    if (lane == 63) ws[wid] = incl;
    __syncthreads();
    int woff = 0;
#pragma unroll
    for (int w = 0; w < 4; w++)
        if (w < wid) woff += ws[w];
    int run = boffs[blockIdx.x] + woff + incl - tsum;
#pragma unroll
    for (int t = 0; t < 4; t++) {
        int i = base + t;
        if (i < N) { starts[i] = run; counts[i] = run; }   // counts = cursor
        run += v[t];
    }
    if (blockIdx.x == 0 && tid == 0) starts[N] = boffs[gridDim.x];
}

// fill CSR; also precompute per-edge norm = dinv[src]
__global__ void k_fill(const void* __restrict__ eidx, const int* __restrict__ flag,
                       int* __restrict__ cursor, int* __restrict__ srcs,
                       float* __restrict__ nrm, const float* __restrict__ dinv,
                       int E) {
    int i = blockIdx.x * blockDim.x + threadIdx.x;
    if (i >= E) return;
    int s, d;
    load_edge(eidx, *flag, E, i, s, d);
    int pos = atomicAdd(&cursor[d], 1);
    srcs[pos] = s;
    nrm[pos] = dinv[s];
}

// ---------------- conversions ----------------------------------------------
__global__ void k_cvt_x(const float* __restrict__ x, unsigned short* __restrict__ o,
                        long long n4) {
    long long i = (long long)blockIdx.x * blockDim.x + threadIdx.x;
    long long stride = (long long)gridDim.x * blockDim.x;
    for (; i < n4; i += stride) {
        float4 v = ((const float4*)x)[i];
        unsigned a = (unsigned)f2bf(v.x) | ((unsigned)f2bf(v.y) << 16);
        unsigned b = (unsigned)f2bf(v.z) | ((unsigned)f2bf(v.w) << 16);
        ((uint2*)o)[i] = make_uint2(a, b);
    }
}

// all 4 weights in one launch: W [K][H] fp32 -> transposed padded [256][256]
__global__ void k_cvt_w4(const float* __restrict__ W0, const float* __restrict__ W1,
                         const float* __restrict__ W2, const float* __restrict__ W3,
                         unsigned short* __restrict__ T0, unsigned short* __restrict__ T1,
                         unsigned short* __restrict__ T2, unsigned short* __restrict__ T3,
                         int K0, int K123, int H) {
    int l = blockIdx.y;
    const float* W = (l == 0) ? W0 : (l == 1) ? W1 : (l == 2) ? W2 : W3;
    unsigned short* T = (l == 0) ? T0 : (l == 1) ? T1 : (l == 2) ? T2 : T3;
    int K = (l == 0) ? K0 : K123;
    int idx = blockIdx.x * blockDim.x + threadIdx.x;
    if (idx >= 256 * 256) return;
    int k = idx & 255, n = idx >> 8;
    float v = (k < K && n < H) ? W[k * H + n] : 0.0f;
    T[n * 256 + k] = f2bf(v);
}

// ---------------- single-pass bf16 MFMA GEMM (layer 1) ---------------------
// C[M][256] = A[M][256] @ W[256][256]; A plain bf16, W transposed bf16.
// 128x128 tile, 4 waves, 4x4 grid of 16x16x32 MFMA; XCD-chunked 1-D grid.
__global__ __launch_bounds__(256) void k_gemm_mfma(
        const unsigned short* __restrict__ A,
        const unsigned short* __restrict__ BT,
        unsigned short* __restrict__ C, int M) {
    __shared__ unsigned short ldsA[4 * 128 * 8];    // chunk c = kq*128+m
    __shared__ unsigned short ldsB[4 * 128 * 8];    // chunk c = kq*128+n

    // xcd-chunked bijective remap
    int g = blockIdx.x, nwg = gridDim.x;
    int q = nwg >> 3, r = nwg & 7;
    int xcd = g & 7, slot = g >> 3;
    int work = (xcd < r) ? xcd * (q + 1) + slot
                         : r * (q + 1) + (xcd - r) * q + slot;
    int col0 = (work & 1) * 128;
    int row0 = (work >> 1) * 128;

    int tid = threadIdx.x;
    int lane = tid & 63;
    int w = tid >> 6;
    int wm = (w & 1) * 64, wn = (w >> 1) * 64;
    int kq = lane >> 4, lr = lane & 15;

    f32x4 acc[4][4] = {};

    for (int k0 = 0; k0 < 256; k0 += 32) {
        __syncthreads();
#pragma unroll
        for (int i = 0; i < 2; i++) {
            int c = (i * 4 + w) * 64 + lane;
            int m = c & 127, kqq = c >> 7;
            int row = row0 + m; if (row >= M) row = M - 1;   // clamp: valid addr
            gl2lds16(&A[(long long)row * 256 + k0 + kqq * 8],
                     &ldsA[(i * 4 + w) * 512]);
        }
#pragma unroll
        for (int i = 0; i < 2; i++) {
            int c = (i * 4 + w) * 64 + lane;
            int n = c & 127, kqq = c >> 7;
            gl2lds16(&BT[(long long)(col0 + n) * 256 + k0 + kqq * 8],
                     &ldsB[(i * 4 + w) * 512]);
        }
        __syncthreads();

        bf16x8 a[4], b[4];
#pragma unroll
        for (int t = 0; t < 4; t++) {
            int m = wm + t * 16 + lr;
            a[t] = *(const bf16x8*)&ldsA[(kq * 128 + m) * 8];
            int n = wn + t * 16 + lr;
            b[t] = *(const bf16x8*)&ldsB[(kq * 128 + n) * 8];
        }
#pragma unroll
        for (int mt = 0; mt < 4; mt++)
#pragma unroll
            for (int nt = 0; nt < 4; nt++)
                acc[mt][nt] = __builtin_amdgcn_mfma_f32_16x16x32_bf16(
                    a[mt], b[nt], acc[mt][nt], 0, 0, 0);
    }

    // epilogue: C/D layout col=lane&15, row=(lane>>4)*4+reg  [m89-verified]
#pragma unroll
    for (int mt = 0; mt < 4; mt++) {
#pragma unroll
        for (int nt = 0; nt < 4; nt++) {
            int col = col0 + wn + nt * 16 + lr;
            int rowb = row0 + wm + mt * 16 + kq * 4;
#pragma unroll
            for (int r2 = 0; r2 < 4; r2++) {
                int row = rowb + r2;
                if (row < M) C[(long long)row * 256 + col] = f2bf(acc[mt][nt][r2]);
            }
        }
    }
}

// ---------------- wave-per-dst CSR aggregation core ------------------------
// 64 lanes = 1 dst row; 4 features/lane (uint2); 8-deep independent batch.
__device__ __forceinline__ void agg_rows(
        const unsigned short* __restrict__ h,
        const int* __restrict__ srcs, const float* __restrict__ nrm,
        const int* __restrict__ starts, int d, int f0, float dd, float* acc) {
    int lane = threadIdx.x & 63;
    int e0 = starts[d], e1 = starts[d + 1];
    int cnt = e1 - e0;
    int cpre = cnt < 64 ? cnt : 64;

    acc[0] = acc[1] = acc[2] = acc[3] = 0.0f;
    {   // self-loop (also warms L1 with row d for masked slots)
        uint2 v = *(const uint2*)&h[((long long)d << 8) + f0];
        fma4(v, dd, acc);
    }
    int sv = 0; float nv = 0.0f;
    if (lane < cpre) { sv = srcs[e0 + lane]; nv = nrm[e0 + lane]; }

    for (int base = 0; base < cpre; base += 8) {
        uint2 vv[8]; float nn[8];
#pragma unroll
        for (int t = 0; t < 8; t++) {
            int j = base + t;                    // <= 63 always
            int s = __shfl(sv, j);
            float n = __shfl(nv, j);
            if (j >= cpre) { s = d; n = 0.0f; }  // wave-uniform mask
            nn[t] = n;
            vv[t] = *(const uint2*)&h[((long long)s << 8) + f0];
        }
#pragma unroll
        for (int t = 0; t < 8; t++) fma4(vv[t], nn[t], acc);
    }
    for (int e = e0 + 64; e < e1; e++) {         // rare: degree > 64
        int s0 = srcs[e];
        float n0 = nrm[e];
        uint2 v0 = *(const uint2*)&h[((long long)s0 << 8) + f0];
        fma4(v0, n0, acc);
    }
}

// ---------------- fused gather + GEMM (middle layers) ----------------------
// Block = 64 dst rows, 512 threads (8 waves). Static LDS = 32 KB.
// launch_bounds (512,4): VGPR cap 128, compiler lands ~64 (r14-proven), the
// 8-deep batch stays in registers; grid 782 -> ~3 blocks/CU, ~24 waves/CU.
__global__ __launch_bounds__(512, 4) void k_fused(
        const unsigned short* __restrict__ h,   // prev layer C, bf16 [N][256]
        const int* __restrict__ srcs, const float* __restrict__ nrm,
        const int* __restrict__ starts, const float* __restrict__ dinv,
        const float* __restrict__ bias,         // gather-layer bias
        const unsigned short* __restrict__ BT,  // next-layer W^T [256][256]
        unsigned short* __restrict__ C,         // out, bf16 [N][256]
        int N, int H) {
    __shared__ unsigned short ldsA[64 * 256];       // 32 KB, swizzled rows

    int tid = threadIdx.x;
    int lane = tid & 63;
    int w = tid >> 6;                                // 0..7
    int row0 = blockIdx.x * 64;

    // ---- phase 1: gather 8 rows per wave ----
    int f0 = lane * 4;
    for (int i = 0; i < 8; i++) {
        int dl = w * 8 + i;
        int d = row0 + dl;
        if (d < N) {
            float dd = dinv[d];
            float acc[4];
            agg_rows(h, srcs, nrm, starts, d, f0, dd, acc);
            unsigned short o[4];
#pragma unroll
            for (int t = 0; t < 4; t++) {
                int f = f0 + t;
                float bb = (f < H) ? bias[f] : 0.0f;
                float v = fmaxf(acc[t] * dd + bb, 0.0f);  // relu; pads stay 0
                o[t] = f2bf(v);
            }
            unsigned o01 = (unsigned)o[0] | ((unsigned)o[1] << 16);
            unsigned o23 = (unsigned)o[2] | ((unsigned)o[3] << 16);
            unsigned boff = (unsigned)(dl * 512 + lane * 8) ^
                            (((unsigned)dl & 7u) << 4);
            *(uint2*)((char*)ldsA + boff) = make_uint2(o01, o23);
        }
    }
    __syncthreads();

    // ---- phase 2: GEMM 64x256, no barriers ----
    int wm = (w & 1) * 32, wn = (w >> 1) * 64;
    int kq = lane >> 4, lr = lane & 15;
    f32x4 acc[2][4] = {};

#pragma unroll
    for (int k0 = 0; k0 < 256; k0 += 32) {
        bf16x8 a[2], b[4];
#pragma unroll
        for (int t = 0; t < 2; t++) {
            int row = wm + t * 16 + lr;
            unsigned boff = (unsigned)(row * 512 + k0 * 2 + kq * 16) ^
                            (((unsigned)row & 7u) << 4);
            a[t] = *(const bf16x8*)((const char*)ldsA + boff);
        }
#pragma unroll
        for (int t = 0; t < 4; t++) {
            int n = wn + t * 16 + lr;
            b[t] = *(const bf16x8*)&BT[(long long)n * 256 + k0 + kq * 8];
        }
#pragma unroll
        for (int mt = 0; mt < 2; mt++)
#pragma unroll
            for (int nt = 0; nt < 4; nt++)
                acc[mt][nt] = __builtin_amdgcn_mfma_f32_16x16x32_bf16(
                    a[mt], b[nt], acc[mt][nt], 0, 0, 0);
    }

    // epilogue: C/D layout col=lane&15, row=(lane>>4)*4+reg
#pragma unroll
    for (int mt = 0; mt < 2; mt++) {
#pragma unroll
        for (int nt = 0; nt < 4; nt++) {
            int col = wn + nt * 16 + lr;
            int rowb = row0 + wm + mt * 16 + kq * 4;
#pragma unroll
            for (int r2 = 0; r2 < 4; r2++) {
                int row = rowb + r2;
                if (row < N) C[(long long)row * 256 + col] = f2bf(acc[mt][nt][r2]);
            }
        }
    }
}

// ---------------- layer-4: gather + fused log_softmax ----------------------
__global__ __launch_bounds__(256) void k_gather_lsm(
        const unsigned short* __restrict__ h,   // bf16 [N][256]
        const int* __restrict__ srcs, const float* __restrict__ nrm,
        const int* __restrict__ starts,
        const float* __restrict__ dinv, const float* __restrict__ bias,
        float* __restrict__ out, int N, int H) {
    int d = blockIdx.x * 4 + (threadIdx.x >> 6);
    if (d >= N) return;
    int lane = threadIdx.x & 63;
    int f0 = lane * 4;
    float dd = dinv[d];

    float acc[4];
    agg_rows(h, srcs, nrm, starts, d, f0, dd, acc);

    float v[4];
    float m = -INFINITY;
#pragma unroll
    for (int t = 0; t < 4; t++) {
        int f = f0 + t;
        float bb = (f < H) ? bias[f] : 0.0f;
        v[t] = acc[t] * dd + bb;
        if (f < H) m = fmaxf(m, v[t]);
    }
#pragma unroll
    for (int off = 32; off > 0; off >>= 1) m = fmaxf(m, __shfl_xor(m, off));
    float s = 0.0f;
#pragma unroll
    for (int t = 0; t < 4; t++) {
        int f = f0 + t;
        if (f < H) s += __expf(v[t] - m);
    }
#pragma unroll
    for (int off = 32; off > 0; off >>= 1) s += __shfl_xor(s, off);
    float lse = m + logf(s);
#pragma unroll
    for (int t = 0; t < 4; t++) {
        int f = f0 + t;
        if (f < H) out[(long long)d * H + f] = v[t] - lse;
    }
}

// ---------------------------------------------------------------------------
extern "C" void kernel_launch(void* const* d_in, const int* in_sizes, int n_in,
                              void* d_out, int out_size, void* d_ws, size_t ws_size,
                              hipStream_t stream) {
    const float* x    = (const float*)d_in[0];
    const void*  eidx = d_in[1];
    const float* W[4] = {(const float*)d_in[2], (const float*)d_in[4],
                         (const float*)d_in[6], (const float*)d_in[8]};
    const float* b[4] = {(const float*)d_in[3], (const float*)d_in[5],
                         (const float*)d_in[7], (const float*)d_in[9]};

    const int H   = in_sizes[3];          // 246
    const int E   = in_sizes[1] / 2;      // 320000
    const int FIN = in_sizes[2] / H;      // 256
    const int N   = in_sizes[0] / FIN;    // 50000

    auto align = [](size_t v) { return (v + 255) / 256 * 256; };
    char* ws = (char*)d_ws;
    size_t off = 0;
    int* flag = (int*)(ws + off);             off += 256;
    float* dinv = (float*)(ws + off);         off += align((size_t)N * 4);
    int* counts = (int*)(ws + off);           off += align((size_t)N * 4);
    int* starts = (int*)(ws + off);           off += align((size_t)(N + 1) * 4);
    int* srcs = (int*)(ws + off);             off += align((size_t)E * 4);
    float* nrm = (float*)(ws + off);          off += align((size_t)E * 4);
    int nb2 = (N + 1023) / 1024;
    int* bsum = (int*)(ws + off);             off += align((size_t)(nb2 + 1) * 4);
    int* boffs = (int*)(ws + off);            off += align((size_t)(nb2 + 1) * 4);
    unsigned short* Wt[4];
    for (int l = 0; l < 4; l++) {
        Wt[l] = (unsigned short*)(ws + off);  off += 256 * 256 * 2;
    }
    size_t actB = align((size_t)N * 256 * 2);
    unsigned short* A0  = (unsigned short*)(ws + off);  off += actB;
    unsigned short* Cb0 = (unsigned short*)(ws + off);  off += actB;
    unsigned short* Cb1 = (unsigned short*)(ws + off);  off += actB;

    int eb = (E + 255) / 256;

    // --- edge dtype detection (+ counts zeroing) ---
    k_flag_init<<<1, 64, 0, stream>>>(flag);
    k_flag_check<<<512, 256, 0, stream>>>((const long long*)eidx, E, (long long)N,
                                          flag, counts, N);

    // --- CSR build ---
    k_count<<<eb, 256, 0, stream>>>(eidx, flag, counts, E);
    k_dinv_bsum<<<nb2, 256, 0, stream>>>(counts, dinv, bsum, N);
    k_scan<<<1, 1024, 0, stream>>>(bsum, boffs, nb2);
    k_scan_final<<<nb2, 256, 0, stream>>>(counts, boffs, starts, N);
    k_fill<<<eb, 256, 0, stream>>>(eidx, flag, counts, srcs, nrm, dinv, E);

    // --- weight + input conversion ---
    k_cvt_w4<<<dim3(256, 4), 256, 0, stream>>>(W[0], W[1], W[2], W[3],
                                               Wt[0], Wt[1], Wt[2], Wt[3],
                                               FIN, H, H);
    k_cvt_x<<<1024, 256, 0, stream>>>(x, A0, (long long)N * FIN / 4);

    int ggrid = 2 * ((N + 127) / 128);
    int fgrid = (N + 63) / 64;
    int gb = (N + 3) / 4;

    // --- layer 1: GEMM only ---
    k_gemm_mfma<<<ggrid, 256, 0, stream>>>(A0, Wt[0], Cb0, N);
    // --- fused: gather(l1)+GEMM(l2), gather(l2)+GEMM(l3), gather(l3)+GEMM(l4)
    k_fused<<<fgrid, 512, 0, stream>>>(Cb0, srcs, nrm, starts, dinv, b[0],
                                       Wt[1], Cb1, N, H);
    k_fused<<<fgrid, 512, 0, stream>>>(Cb1, srcs, nrm, starts, dinv, b[1],
                                       Wt[2], Cb0, N, H);
    k_fused<<<fgrid, 512, 0, stream>>>(Cb0, srcs, nrm, starts, dinv, b[2],
                                       Wt[3], Cb1, N, H);
    // --- layer 4 aggregation + log_softmax ---
    k_gather_lsm<<<gb, 256, 0, stream>>>(Cb1, srcs, nrm, starts, dinv, b[3],
                                         (float*)d_out, N, H);
}

// Round 7
// 460.872 us; speedup vs baseline: 1.0271x; 1.0028x over previous
//
#include <hip/hip_runtime.h>
#include <cstdint>
#include <cstddef>

// ---------------------------------------------------------------------------
// 4-layer GCN. Round 17: force REAL 8-deep memory-level parallelism.
// r16 post-mortem: VGPR stayed 36 -> compiler scheduled the "8-deep" gather
// batch at ~2-deep (load->use interleaved), so fused gather ran at 1.39 TB/s
// vs the 2.7 TB/s fabric ceiling the (21-wave/CU) standalone gather reaches.
// Fix: __builtin_amdgcn_sched_barrier(0) between the 8-load loop and the
// consume loop in agg_rows -> all 8 global_load_dwordx2 pinned in flight.
// Structure otherwise identical to r16.
// ---------------------------------------------------------------------------

typedef __bf16 bf16x8 __attribute__((ext_vector_type(8)));
typedef float f32x4 __attribute__((ext_vector_type(4)));

__device__ __forceinline__ unsigned short f2bf(float v) {   // RNE
    union { float f; unsigned u; } x; x.f = v;
    unsigned r = x.u + 0x7fff + ((x.u >> 16) & 1);
    return (unsigned short)(r >> 16);
}
__device__ __forceinline__ float bf2f(unsigned short h) {
    union { unsigned u; float f; } x; x.u = (unsigned)h << 16; return x.f;
}

// async global->LDS, 16B per lane; lds base must be wave-uniform
__device__ __forceinline__ void gl2lds16(const void* g, void* l) {
    __builtin_amdgcn_global_load_lds(
        (const __attribute__((address_space(1))) unsigned int*)g,
        (__attribute__((address_space(3))) unsigned int*)l, 16, 0, 0);
}

// acc[0..3] += bf16x4(v) * n
__device__ __forceinline__ void fma4(const uint2 v, float n, float* acc) {
    acc[0] += bf2f((unsigned short)(v.x & 0xffff)) * n;
    acc[1] += bf2f((unsigned short)(v.x >> 16)) * n;
    acc[2] += bf2f((unsigned short)(v.y & 0xffff)) * n;
    acc[3] += bf2f((unsigned short)(v.y >> 16)) * n;
}

// ---------------- edge-index dtype detection + counts zero -----------------
__global__ void k_flag_init(int* flag) {
    if (blockIdx.x == 0 && threadIdx.x == 0) *flag = 1;
}

__global__ void k_flag_check(const long long* __restrict__ p, int E, long long N,
                             int* flag, int* __restrict__ counts, int Ncnt) {
    long long i = (long long)blockIdx.x * blockDim.x + threadIdx.x;
    long long stride = (long long)gridDim.x * blockDim.x;
    for (long long j = i; j < Ncnt; j += stride) counts[j] = 0;   // fused zero
    for (; i < E; i += stride) {
        long long v = p[i];
        if (v < 0 || v >= N) *flag = 0;
    }
}

__device__ __forceinline__ void load_edge(const void* eidx, int fl, int E, int i,
                                          int& s, int& d) {
    if (fl) {
        s = (int)((const long long*)eidx)[i];
        d = (int)((const long long*)eidx)[E + i];
    } else {
        s = ((const int*)eidx)[i];
        d = ((const int*)eidx)[E + i];
    }
}

// ---------------- CSR build -------------------------------------------------
__global__ void k_count(const void* __restrict__ eidx, const int* __restrict__ flag,
                        int* __restrict__ counts, int E) {
    int i = blockIdx.x * blockDim.x + threadIdx.x;
    if (i >= E) return;
    int s, d;
    load_edge(eidx, *flag, E, i, s, d);
    atomicAdd(&counts[d], 1);
}

// dinv + per-1024-chunk sums, merged (256 threads, 4 elems/thread)
__global__ __launch_bounds__(256) void k_dinv_bsum(
        const int* __restrict__ counts, float* __restrict__ dinv,
        int* __restrict__ bsum, int N) {
    __shared__ int ws[4];
    int tid = threadIdx.x, lane = tid & 63, wid = tid >> 6;
    int base = blockIdx.x * 1024 + tid * 4;
    int v[4];
#pragma unroll
    for (int t = 0; t < 4; t++) {
        int i = base + t;
        v[t] = (i < N) ? counts[i] : 0;
        if (i < N) dinv[i] = rsqrtf((float)v[t] + 1.0f);
    }
    int s = v[0] + v[1] + v[2] + v[3];
#pragma unroll
    for (int off = 32; off > 0; off >>= 1) s += __shfl_xor(s, off);
    if (lane == 0) ws[wid] = s;
    __syncthreads();
    if (tid == 0) bsum[blockIdx.x] = ws[0] + ws[1] + ws[2] + ws[3];
}

// small single-block exclusive scan (block sums; n is small)
__global__ __launch_bounds__(1024) void k_scan(const int* __restrict__ counts,
                                               int* __restrict__ starts, int N) {
    __shared__ int wsum[16];
    __shared__ int wscan[16];
    __shared__ int s_carry;
    int tid = threadIdx.x;
    int lane = tid & 63, wid = tid >> 6;
    if (tid == 0) s_carry = 0;
    __syncthreads();
    for (int base = 0; base < N; base += 1024) {
        int i = base + tid;
        int v = (i < N) ? counts[i] : 0;
        int incl = v;
#pragma unroll
        for (int off = 1; off < 64; off <<= 1) {
            int t = __shfl_up(incl, off);
            if (lane >= off) incl += t;
        }
        if (lane == 63) wsum[wid] = incl;
        __syncthreads();
        if (wid == 0 && lane < 16) {
            int w = wsum[lane];
#pragma unroll
            for (int off = 1; off < 16; off <<= 1) {
                int t = __shfl_up(w, off);
                if (lane >= off) w += t;
            }
            wscan[lane] = w;
        }
        __syncthreads();
        int woff = (wid > 0) ? wscan[wid - 1] : 0;
        int excl = s_carry + woff + incl - v;
        if (i < N) starts[i] = excl;
        int total = wscan[15];
        __syncthreads();
        if (tid == 0) s_carry += total;
        __syncthreads();
    }
    if (tid == 0) starts[N] = s_carry;
}

// final: per-1024-chunk exclusive scan + block offset; also writes cursor copy
__global__ __launch_bounds__(256) void k_scan_final(
        int* __restrict__ counts, const int* __restrict__ boffs,
        int* __restrict__ starts, int N) {
    __shared__ int ws[4];
    int tid = threadIdx.x, lane = tid & 63, wid = tid >> 6;
    int base = blockIdx.x * 1024 + tid * 4;
    int v[4];
#pragma unroll
    for (int t = 0; t < 4; t++) {
        int i = base + t;
        v[t] = (i < N) ? counts[i] : 0;
    }
    int tsum = v[0] + v[1] + v[2] + v[3];
    int incl = tsum;
#pragma unroll
    for (int off = 1; off < 64; off <<= 1) {
        int t = __shfl_up(incl, off);
        if (lane >= off) incl += t;
    }
    if (lane == 63) ws[wid] = incl;
    __syncthreads();
    int woff = 0;
#pragma unroll
    for (int w = 0; w < 4; w++)
        if (w < wid) woff += ws[w];
    int run = boffs[blockIdx.x] + woff + incl - tsum;
#pragma unroll
    for (int t = 0; t < 4; t++) {
        int i = base + t;
        if (i < N) { starts[i] = run; counts[i] = run; }   // counts = cursor
        run += v[t];
    }
    if (blockIdx.x == 0 && tid == 0) starts[N] = boffs[gridDim.x];
}

// fill CSR; also precompute per-edge norm = dinv[src]
__global__ void k_fill(const void* __restrict__ eidx, const int* __restrict__ flag,
                       int* __restrict__ cursor, int* __restrict__ srcs,
                       float* __restrict__ nrm, const float* __restrict__ dinv,
                       int E) {
    int i = blockIdx.x * blockDim.x + threadIdx.x;
    if (i >= E) return;
    int s, d;
    load_edge(eidx, *flag, E, i, s, d);
    int pos = atomicAdd(&cursor[d], 1);
    srcs[pos] = s;
    nrm[pos] = dinv[s];
}

// ---------------- conversions ----------------------------------------------
__global__ void k_cvt_x(const float* __restrict__ x, unsigned short* __restrict__ o,
                        long long n4) {
    long long i = (long long)blockIdx.x * blockDim.x + threadIdx.x;
    long long stride = (long long)gridDim.x * blockDim.x;
    for (; i < n4; i += stride) {
        float4 v = ((const float4*)x)[i];
        unsigned a = (unsigned)f2bf(v.x) | ((unsigned)f2bf(v.y) << 16);
        unsigned b = (unsigned)f2bf(v.z) | ((unsigned)f2bf(v.w) << 16);
        ((uint2*)o)[i] = make_uint2(a, b);
    }
}

// all 4 weights in one launch: W [K][H] fp32 -> transposed padded [256][256]
__global__ void k_cvt_w4(const float* __restrict__ W0, const float* __restrict__ W1,
                         const float* __restrict__ W2, const float* __restrict__ W3,
                         unsigned short* __restrict__ T0, unsigned short* __restrict__ T1,
                         unsigned short* __restrict__ T2, unsigned short* __restrict__ T3,
                         int K0, int K123, int H) {
    int l = blockIdx.y;
    const float* W = (l == 0) ? W0 : (l == 1) ? W1 : (l == 2) ? W2 : W3;
    unsigned short* T = (l == 0) ? T0 : (l == 1) ? T1 : (l == 2) ? T2 : T3;
    int K = (l == 0) ? K0 : K123;
    int idx = blockIdx.x * blockDim.x + threadIdx.x;
    if (idx >= 256 * 256) return;
    int k = idx & 255, n = idx >> 8;
    float v = (k < K && n < H) ? W[k * H + n] : 0.0f;
    T[n * 256 + k] = f2bf(v);
}

// ---------------- single-pass bf16 MFMA GEMM (layer 1) ---------------------
// C[M][256] = A[M][256] @ W[256][256]; A plain bf16, W transposed bf16.
// 128x128 tile, 4 waves, 4x4 grid of 16x16x32 MFMA; XCD-chunked 1-D grid.
__global__ __launch_bounds__(256) void k_gemm_mfma(
        const unsigned short* __restrict__ A,
        const unsigned short* __restrict__ BT,
        unsigned short* __restrict__ C, int M) {
    __shared__ unsigned short ldsA[4 * 128 * 8];    // chunk c = kq*128+m
    __shared__ unsigned short ldsB[4 * 128 * 8];    // chunk c = kq*128+n

    // xcd-chunked bijective remap
    int g = blockIdx.x, nwg = gridDim.x;
    int q = nwg >> 3, r = nwg & 7;
    int xcd = g & 7, slot = g >> 3;
    int work = (xcd < r) ? xcd * (q + 1) + slot
                         : r * (q + 1) + (xcd - r) * q + slot;
    int col0 = (work & 1) * 128;
    int row0 = (work >> 1) * 128;

    int tid = threadIdx.x;
    int lane = tid & 63;
    int w = tid >> 6;
    int wm = (w & 1) * 64, wn = (w >> 1) * 64;
    int kq = lane >> 4, lr = lane & 15;

    f32x4 acc[4][4] = {};

    for (int k0 = 0; k0 < 256; k0 += 32) {
        __syncthreads();
#pragma unroll
        for (int i = 0; i < 2; i++) {
            int c = (i * 4 + w) * 64 + lane;
            int m = c & 127, kqq = c >> 7;
            int row = row0 + m; if (row >= M) row = M - 1;   // clamp: valid addr
            gl2lds16(&A[(long long)row * 256 + k0 + kqq * 8],
                     &ldsA[(i * 4 + w) * 512]);
        }
#pragma unroll
        for (int i = 0; i < 2; i++) {
            int c = (i * 4 + w) * 64 + lane;
            int n = c & 127, kqq = c >> 7;
            gl2lds16(&BT[(long long)(col0 + n) * 256 + k0 + kqq * 8],
                     &ldsB[(i * 4 + w) * 512]);
        }
        __syncthreads();

        bf16x8 a[4], b[4];
#pragma unroll
        for (int t = 0; t < 4; t++) {
            int m = wm + t * 16 + lr;
            a[t] = *(const bf16x8*)&ldsA[(kq * 128 + m) * 8];
            int n = wn + t * 16 + lr;
            b[t] = *(const bf16x8*)&ldsB[(kq * 128 + n) * 8];
        }
#pragma unroll
        for (int mt = 0; mt < 4; mt++)
#pragma unroll
            for (int nt = 0; nt < 4; nt++)
                acc[mt][nt] = __builtin_amdgcn_mfma_f32_16x16x32_bf16(
                    a[mt], b[nt], acc[mt][nt], 0, 0, 0);
    }

    // epilogue: C/D layout col=lane&15, row=(lane>>4)*4+reg  [m89-verified]
#pragma unroll
    for (int mt = 0; mt < 4; mt++) {
#pragma unroll
        for (int nt = 0; nt < 4; nt++) {
            int col = col0 + wn + nt * 16 + lr;
            int rowb = row0 + wm + mt * 16 + kq * 4;
#pragma unroll
            for (int r2 = 0; r2 < 4; r2++) {
                int row = rowb + r2;
                if (row < M) C[(long long)row * 256 + col] = f2bf(acc[mt][nt][r2]);
            }
        }
    }
}

// ---------------- wave-per-dst CSR aggregation core ------------------------
// 64 lanes = 1 dst row; 4 features/lane (uint2); 8-deep batch with a
// sched_barrier(0) pinning all 8 loads in flight before any consume.
__device__ __forceinline__ void agg_rows(
        const unsigned short* __restrict__ h,
        const int* __restrict__ srcs, const float* __restrict__ nrm,
        const int* __restrict__ starts, int d, int f0, float dd, float* acc) {
    int lane = threadIdx.x & 63;
    int e0 = starts[d], e1 = starts[d + 1];
    int cnt = e1 - e0;
    int cpre = cnt < 64 ? cnt : 64;

    acc[0] = acc[1] = acc[2] = acc[3] = 0.0f;
    {   // self-loop (also warms L1 with row d for masked slots)
        uint2 v = *(const uint2*)&h[((long long)d << 8) + f0];
        fma4(v, dd, acc);
    }
    int sv = 0; float nv = 0.0f;
    if (lane < cpre) { sv = srcs[e0 + lane]; nv = nrm[e0 + lane]; }

    for (int base = 0; base < cpre; base += 8) {
        uint2 vv[8]; float nn[8];
#pragma unroll
        for (int t = 0; t < 8; t++) {
            int j = base + t;                    // <= 63 always
            int s = __shfl(sv, j);
            float n = __shfl(nv, j);
            if (j >= cpre) { s = d; n = 0.0f; }  // wave-uniform mask
            nn[t] = n;
            vv[t] = *(const uint2*)&h[((long long)s << 8) + f0];
        }
        // pin: all 8 independent global loads issued before any FMA consumes
        __builtin_amdgcn_sched_barrier(0);
#pragma unroll
        for (int t = 0; t < 8; t++) fma4(vv[t], nn[t], acc);
    }
    for (int e = e0 + 64; e < e1; e++) {         // rare: degree > 64
        int s0 = srcs[e];
        float n0 = nrm[e];
        uint2 v0 = *(const uint2*)&h[((long long)s0 << 8) + f0];
        fma4(v0, n0, acc);
    }
}

// ---------------- fused gather + GEMM (middle layers) ----------------------
// Block = 64 dst rows, 512 threads (8 waves). Static LDS = 32 KB.
__global__ __launch_bounds__(512, 4) void k_fused(
        const unsigned short* __restrict__ h,   // prev layer C, bf16 [N][256]
        const int* __restrict__ srcs, const float* __restrict__ nrm,
        const int* __restrict__ starts, const float* __restrict__ dinv,
        const float* __restrict__ bias,         // gather-layer bias
        const unsigned short* __restrict__ BT,  // next-layer W^T [256][256]
        unsigned short* __restrict__ C,         // out, bf16 [N][256]
        int N, int H) {
    __shared__ unsigned short ldsA[64 * 256];       // 32 KB, swizzled rows

    int tid = threadIdx.x;
    int lane = tid & 63;
    int w = tid >> 6;                                // 0..7
    int row0 = blockIdx.x * 64;

    // ---- phase 1: gather 8 rows per wave ----
    int f0 = lane * 4;
    for (int i = 0; i < 8; i++) {
        int dl = w * 8 + i;
        int d = row0 + dl;
        if (d < N) {
            float dd = dinv[d];
            float acc[4];
            agg_rows(h, srcs, nrm, starts, d, f0, dd, acc);
            unsigned short o[4];
#pragma unroll
            for (int t = 0; t < 4; t++) {
                int f = f0 + t;
                float bb = (f < H) ? bias[f] : 0.0f;
                float v = fmaxf(acc[t] * dd + bb, 0.0f);  // relu; pads stay 0
                o[t] = f2bf(v);
            }
            unsigned o01 = (unsigned)o[0] | ((unsigned)o[1] << 16);
            unsigned o23 = (unsigned)o[2] | ((unsigned)o[3] << 16);
            unsigned boff = (unsigned)(dl * 512 + lane * 8) ^
                            (((unsigned)dl & 7u) << 4);
            *(uint2*)((char*)ldsA + boff) = make_uint2(o01, o23);
        }
    }
    __syncthreads();

    // ---- phase 2: GEMM 64x256, no barriers ----
    int wm = (w & 1) * 32, wn = (w >> 1) * 64;
    int kq = lane >> 4, lr = lane & 15;
    f32x4 acc[2][4] = {};

#pragma unroll
    for (int k0 = 0; k0 < 256; k0 += 32) {
        bf16x8 a[2], b[4];
#pragma unroll
        for (int t = 0; t < 2; t++) {
            int row = wm + t * 16 + lr;
            unsigned boff = (unsigned)(row * 512 + k0 * 2 + kq * 16) ^
                            (((unsigned)row & 7u) << 4);
            a[t] = *(const bf16x8*)((const char*)ldsA + boff);
        }
#pragma unroll
        for (int t = 0; t < 4; t++) {
            int n = wn + t * 16 + lr;
            b[t] = *(const bf16x8*)&BT[(long long)n * 256 + k0 + kq * 8];
        }
#pragma unroll
        for (int mt = 0; mt < 2; mt++)
#pragma unroll
            for (int nt = 0; nt < 4; nt++)
                acc[mt][nt] = __builtin_amdgcn_mfma_f32_16x16x32_bf16(
                    a[mt], b[nt], acc[mt][nt], 0, 0, 0);
    }

    // epilogue: C/D layout col=lane&15, row=(lane>>4)*4+reg
#pragma unroll
    for (int mt = 0; mt < 2; mt++) {
#pragma unroll
        for (int nt = 0; nt < 4; nt++) {
            int col = wn + nt * 16 + lr;
            int rowb = row0 + wm + mt * 16 + kq * 4;
#pragma unroll
            for (int r2 = 0; r2 < 4; r2++) {
                int row = rowb + r2;
                if (row < N) C[(long long)row * 256 + col] = f2bf(acc[mt][nt][r2]);
            }
        }
    }
}

// ---------------- layer-4: gather + fused log_softmax ----------------------
__global__ __launch_bounds__(256) void k_gather_lsm(
        const unsigned short* __restrict__ h,   // bf16 [N][256]
        const int* __restrict__ srcs, const float* __restrict__ nrm,
        const int* __restrict__ starts,
        const float* __restrict__ dinv, const float* __restrict__ bias,
        float* __restrict__ out, int N, int H) {
    int d = blockIdx.x * 4 + (threadIdx.x >> 6);
    if (d >= N) return;
    int lane = threadIdx.x & 63;
    int f0 = lane * 4;
    float dd = dinv[d];

    float acc[4];
    agg_rows(h, srcs, nrm, starts, d, f0, dd, acc);

    float v[4];
    float m = -INFINITY;
#pragma unroll
    for (int t = 0; t < 4; t++) {
        int f = f0 + t;
        float bb = (f < H) ? bias[f] : 0.0f;
        v[t] = acc[t] * dd + bb;
        if (f < H) m = fmaxf(m, v[t]);
    }
#pragma unroll
    for (int off = 32; off > 0; off >>= 1) m = fmaxf(m, __shfl_xor(m, off));
    float s = 0.0f;
#pragma unroll
    for (int t = 0; t < 4; t++) {
        int f = f0 + t;
        if (f < H) s += __expf(v[t] - m);
    }
#pragma unroll
    for (int off = 32; off > 0; off >>= 1) s += __shfl_xor(s, off);
    float lse = m + logf(s);
#pragma unroll
    for (int t = 0; t < 4; t++) {
        int f = f0 + t;
        if (f < H) out[(long long)d * H + f] = v[t] - lse;
    }
}

// ---------------------------------------------------------------------------
extern "C" void kernel_launch(void* const* d_in, const int* in_sizes, int n_in,
                              void* d_out, int out_size, void* d_ws, size_t ws_size,
                              hipStream_t stream) {
    const float* x    = (const float*)d_in[0];
    const void*  eidx = d_in[1];
    const float* W[4] = {(const float*)d_in[2], (const float*)d_in[4],
                         (const float*)d_in[6], (const float*)d_in[8]};
    const float* b[4] = {(const float*)d_in[3], (const float*)d_in[5],
                         (const float*)d_in[7], (const float*)d_in[9]};

    const int H   = in_sizes[3];          // 246
    const int E   = in_sizes[1] / 2;      // 320000
    const int FIN = in_sizes[2] / H;      // 256
    const int N   = in_sizes[0] / FIN;    // 50000

    auto align = [](size_t v) { return (v + 255) / 256 * 256; };
    char* ws = (char*)d_ws;
    size_t off = 0;
    int* flag = (int*)(ws + off);             off += 256;
    float* dinv = (float*)(ws + off);         off += align((size_t)N * 4);
    int* counts = (int*)(ws + off);           off += align((size_t)N * 4);
    int* starts = (int*)(ws + off);           off += align((size_t)(N + 1) * 4);
    int* srcs = (int*)(ws + off);             off += align((size_t)E * 4);
    float* nrm = (float*)(ws + off);          off += align((size_t)E * 4);
    int nb2 = (N + 1023) / 1024;
    int* bsum = (int*)(ws + off);             off += align((size_t)(nb2 + 1) * 4);
    int* boffs = (int*)(ws + off);            off += align((size_t)(nb2 + 1) * 4);
    unsigned short* Wt[4];
    for (int l = 0; l < 4; l++) {
        Wt[l] = (unsigned short*)(ws + off);  off += 256 * 256 * 2;
    }
    size_t actB = align((size_t)N * 256 * 2);
    unsigned short* A0  = (unsigned short*)(ws + off);  off += actB;
    unsigned short* Cb0 = (unsigned short*)(ws + off);  off += actB;
    unsigned short* Cb1 = (unsigned short*)(ws + off);  off += actB;

    int eb = (E + 255) / 256;

    // --- edge dtype detection (+ counts zeroing) ---
    k_flag_init<<<1, 64, 0, stream>>>(flag);
    k_flag_check<<<512, 256, 0, stream>>>((const long long*)eidx, E, (long long)N,
                                          flag, counts, N);

    // --- CSR build ---
    k_count<<<eb, 256, 0, stream>>>(eidx, flag, counts, E);
    k_dinv_bsum<<<nb2, 256, 0, stream>>>(counts, dinv, bsum, N);
    k_scan<<<1, 1024, 0, stream>>>(bsum, boffs, nb2);
    k_scan_final<<<nb2, 256, 0, stream>>>(counts, boffs, starts, N);
    k_fill<<<eb, 256, 0, stream>>>(eidx, flag, counts, srcs, nrm, dinv, E);

    // --- weight + input conversion ---
    k_cvt_w4<<<dim3(256, 4), 256, 0, stream>>>(W[0], W[1], W[2], W[3],
                                               Wt[0], Wt[1], Wt[2], Wt[3],
                                               FIN, H, H);
    k_cvt_x<<<1024, 256, 0, stream>>>(x, A0, (long long)N * FIN / 4);

    int ggrid = 2 * ((N + 127) / 128);
    int fgrid = (N + 63) / 64;
    int gb = (N + 3) / 4;

    // --- layer 1: GEMM only ---
    k_gemm_mfma<<<ggrid, 256, 0, stream>>>(A0, Wt[0], Cb0, N);
    // --- fused: gather(l1)+GEMM(l2), gather(l2)+GEMM(l3), gather(l3)+GEMM(l4)
    k_fused<<<fgrid, 512, 0, stream>>>(Cb0, srcs, nrm, starts, dinv, b[0],
                                       Wt[1], Cb1, N, H);
    k_fused<<<fgrid, 512, 0, stream>>>(Cb1, srcs, nrm, starts, dinv, b[1],
                                       Wt[2], Cb0, N, H);
    k_fused<<<fgrid, 512, 0, stream>>>(Cb0, srcs, nrm, starts, dinv, b[2],
                                       Wt[3], Cb1, N, H);
    // --- layer 4 aggregation + log_softmax ---
    k_gather_lsm<<<gb, 256, 0, stream>>>(Cb1, srcs, nrm, starts, dinv, b[3],
                                         (float*)d_out, N, H);
}

// Round 8
// 454.954 us; speedup vs baseline: 1.0405x; 1.0130x over previous
//
#include <hip/hip_runtime.h>
#include <cstdint>
#include <cstddef>

// ---------------------------------------------------------------------------
// 4-layer GCN. Round 18: revert to split gather/GEMM structure (r12, best
// measured 421.6us) + r16 preproc merges. New: gathers process 2 dst rows
// per wave (two 32-lane groups, uint4 = 8 bf16/lane) -> one load instruction
// moves 1KB (2 rows) instead of 512B, halving load-issue per edge. Tests the
// per-CU memory-instruction-rate hypothesis for the 2.7 TB/s gather ceiling.
// ---------------------------------------------------------------------------

typedef __bf16 bf16x8 __attribute__((ext_vector_type(8)));
typedef float f32x4 __attribute__((ext_vector_type(4)));

__device__ __forceinline__ unsigned short f2bf(float v) {   // RNE
    union { float f; unsigned u; } x; x.f = v;
    unsigned r = x.u + 0x7fff + ((x.u >> 16) & 1);
    return (unsigned short)(r >> 16);
}
__device__ __forceinline__ float bf2f(unsigned short h) {
    union { unsigned u; float f; } x; x.u = (unsigned)h << 16; return x.f;
}

// async global->LDS, 16B per lane; lds base must be wave-uniform
__device__ __forceinline__ void gl2lds16(const void* g, void* l) {
    __builtin_amdgcn_global_load_lds(
        (const __attribute__((address_space(1))) unsigned int*)g,
        (__attribute__((address_space(3))) unsigned int*)l, 16, 0, 0);
}

// acc[0..7] += bf16x8(v as uint4) * n
__device__ __forceinline__ void fma8(const uint4 v, float n, float* acc) {
    acc[0] += bf2f((unsigned short)(v.x & 0xffff)) * n;
    acc[1] += bf2f((unsigned short)(v.x >> 16)) * n;
    acc[2] += bf2f((unsigned short)(v.y & 0xffff)) * n;
    acc[3] += bf2f((unsigned short)(v.y >> 16)) * n;
    acc[4] += bf2f((unsigned short)(v.z & 0xffff)) * n;
    acc[5] += bf2f((unsigned short)(v.z >> 16)) * n;
    acc[6] += bf2f((unsigned short)(v.w & 0xffff)) * n;
    acc[7] += bf2f((unsigned short)(v.w >> 16)) * n;
}

// ---------------- edge-index dtype detection + counts zero -----------------
__global__ void k_flag_init(int* flag) {
    if (blockIdx.x == 0 && threadIdx.x == 0) *flag = 1;
}

__global__ void k_flag_check(const long long* __restrict__ p, int E, long long N,
                             int* flag, int* __restrict__ counts, int Ncnt) {
    long long i = (long long)blockIdx.x * blockDim.x + threadIdx.x;
    long long stride = (long long)gridDim.x * blockDim.x;
    for (long long j = i; j < Ncnt; j += stride) counts[j] = 0;   // fused zero
    for (; i < E; i += stride) {
        long long v = p[i];
        if (v < 0 || v >= N) *flag = 0;
    }
}

__device__ __forceinline__ void load_edge(const void* eidx, int fl, int E, int i,
                                          int& s, int& d) {
    if (fl) {
        s = (int)((const long long*)eidx)[i];
        d = (int)((const long long*)eidx)[E + i];
    } else {
        s = ((const int*)eidx)[i];
        d = ((const int*)eidx)[E + i];
    }
}

// ---------------- CSR build -------------------------------------------------
__global__ void k_count(const void* __restrict__ eidx, const int* __restrict__ flag,
                        int* __restrict__ counts, int E) {
    int i = blockIdx.x * blockDim.x + threadIdx.x;
    if (i >= E) return;
    int s, d;
    load_edge(eidx, *flag, E, i, s, d);
    atomicAdd(&counts[d], 1);
}

// dinv + per-1024-chunk sums, merged (256 threads, 4 elems/thread)
__global__ __launch_bounds__(256) void k_dinv_bsum(
        const int* __restrict__ counts, float* __restrict__ dinv,
        int* __restrict__ bsum, int N) {
    __shared__ int ws[4];
    int tid = threadIdx.x, lane = tid & 63, wid = tid >> 6;
    int base = blockIdx.x * 1024 + tid * 4;
    int v[4];
#pragma unroll
    for (int t = 0; t < 4; t++) {
        int i = base + t;
        v[t] = (i < N) ? counts[i] : 0;
        if (i < N) dinv[i] = rsqrtf((float)v[t] + 1.0f);
    }
    int s = v[0] + v[1] + v[2] + v[3];
#pragma unroll
    for (int off = 32; off > 0; off >>= 1) s += __shfl_xor(s, off);
    if (lane == 0) ws[wid] = s;
    __syncthreads();
    if (tid == 0) bsum[blockIdx.x] = ws[0] + ws[1] + ws[2] + ws[3];
}

// small single-block exclusive scan (block sums; n is small)
__global__ __launch_bounds__(1024) void k_scan(const int* __restrict__ counts,
                                               int* __restrict__ starts, int N) {
    __shared__ int wsum[16];
    __shared__ int wscan[16];
    __shared__ int s_carry;
    int tid = threadIdx.x;
    int lane = tid & 63, wid = tid >> 6;
    if (tid == 0) s_carry = 0;
    __syncthreads();
    for (int base = 0; base < N; base += 1024) {
        int i = base + tid;
        int v = (i < N) ? counts[i] : 0;
        int incl = v;
#pragma unroll
        for (int off = 1; off < 64; off <<= 1) {
            int t = __shfl_up(incl, off);
            if (lane >= off) incl += t;
        }
        if (lane == 63) wsum[wid] = incl;
        __syncthreads();
        if (wid == 0 && lane < 16) {
            int w = wsum[lane];
#pragma unroll
            for (int off = 1; off < 16; off <<= 1) {
                int t = __shfl_up(w, off);
                if (lane >= off) w += t;
            }
            wscan[lane] = w;
        }
        __syncthreads();
        int woff = (wid > 0) ? wscan[wid - 1] : 0;
        int excl = s_carry + woff + incl - v;
        if (i < N) starts[i] = excl;
        int total = wscan[15];
        __syncthreads();
        if (tid == 0) s_carry += total;
        __syncthreads();
    }
    if (tid == 0) starts[N] = s_carry;
}

// final: per-1024-chunk exclusive scan + block offset; also writes cursor copy
__global__ __launch_bounds__(256) void k_scan_final(
        int* __restrict__ counts, const int* __restrict__ boffs,
        int* __restrict__ starts, int N) {
    __shared__ int ws[4];
    int tid = threadIdx.x, lane = tid & 63, wid = tid >> 6;
    int base = blockIdx.x * 1024 + tid * 4;
    int v[4];
#pragma unroll
    for (int t = 0; t < 4; t++) {
        int i = base + t;
        v[t] = (i < N) ? counts[i] : 0;
    }
    int tsum = v[0] + v[1] + v[2] + v[3];
    int incl = tsum;
#pragma unroll
    for (int off = 1; off < 64; off <<= 1) {
        int t = __shfl_up(incl, off);
        if (lane >= off) incl += t;
    }
    if (lane == 63) ws[wid] = incl;
    __syncthreads();
    int woff = 0;
#pragma unroll
    for (int w = 0; w < 4; w++)
        if (w < wid) woff += ws[w];
    int run = boffs[blockIdx.x] + woff + incl - tsum;
#pragma unroll
    for (int t = 0; t < 4; t++) {
        int i = base + t;
        if (i < N) { starts[i] = run; counts[i] = run; }   // counts = cursor
        run += v[t];
    }
    if (blockIdx.x == 0 && tid == 0) starts[N] = boffs[gridDim.x];
}

// fill CSR; also precompute per-edge norm = dinv[src]
__global__ void k_fill(const void* __restrict__ eidx, const int* __restrict__ flag,
                       int* __restrict__ cursor, int* __restrict__ srcs,
                       float* __restrict__ nrm, const float* __restrict__ dinv,
                       int E) {
    int i = blockIdx.x * blockDim.x + threadIdx.x;
    if (i >= E) return;
    int s, d;
    load_edge(eidx, *flag, E, i, s, d);
    int pos = atomicAdd(&cursor[d], 1);
    srcs[pos] = s;
    nrm[pos] = dinv[s];
}

// ---------------- conversions ----------------------------------------------
__global__ void k_cvt_x(const float* __restrict__ x, unsigned short* __restrict__ o,
                        long long n4) {
    long long i = (long long)blockIdx.x * blockDim.x + threadIdx.x;
    long long stride = (long long)gridDim.x * blockDim.x;
    for (; i < n4; i += stride) {
        float4 v = ((const float4*)x)[i];
        unsigned a = (unsigned)f2bf(v.x) | ((unsigned)f2bf(v.y) << 16);
        unsigned b = (unsigned)f2bf(v.z) | ((unsigned)f2bf(v.w) << 16);
        ((uint2*)o)[i] = make_uint2(a, b);
    }
}

// all 4 weights in one launch: W [K][H] fp32 -> transposed padded [256][256]
__global__ void k_cvt_w4(const float* __restrict__ W0, const float* __restrict__ W1,
                         const float* __restrict__ W2, const float* __restrict__ W3,
                         unsigned short* __restrict__ T0, unsigned short* __restrict__ T1,
                         unsigned short* __restrict__ T2, unsigned short* __restrict__ T3,
                         int K0, int K123, int H) {
    int l = blockIdx.y;
    const float* W = (l == 0) ? W0 : (l == 1) ? W1 : (l == 2) ? W2 : W3;
    unsigned short* T = (l == 0) ? T0 : (l == 1) ? T1 : (l == 2) ? T2 : T3;
    int K = (l == 0) ? K0 : K123;
    int idx = blockIdx.x * blockDim.x + threadIdx.x;
    if (idx >= 256 * 256) return;
    int k = idx & 255, n = idx >> 8;
    float v = (k < K && n < H) ? W[k * H + n] : 0.0f;
    T[n * 256 + k] = f2bf(v);
}

// ---------------- single-pass bf16 MFMA GEMM -------------------------------
// C[M][256] = A[M][256] @ W[256][256]; A plain bf16, W transposed bf16.
// 128x128 tile, 4 waves, 4x4 grid of 16x16x32 MFMA; XCD-chunked 1-D grid.
__global__ __launch_bounds__(256) void k_gemm_mfma(
        const unsigned short* __restrict__ A,
        const unsigned short* __restrict__ BT,
        unsigned short* __restrict__ C, int M) {
    __shared__ unsigned short ldsA[4 * 128 * 8];    // chunk c = kq*128+m
    __shared__ unsigned short ldsB[4 * 128 * 8];    // chunk c = kq*128+n

    // xcd-chunked bijective remap
    int g = blockIdx.x, nwg = gridDim.x;
    int q = nwg >> 3, r = nwg & 7;
    int xcd = g & 7, slot = g >> 3;
    int work = (xcd < r) ? xcd * (q + 1) + slot
                         : r * (q + 1) + (xcd - r) * q + slot;
    int col0 = (work & 1) * 128;
    int row0 = (work >> 1) * 128;

    int tid = threadIdx.x;
    int lane = tid & 63;
    int w = tid >> 6;
    int wm = (w & 1) * 64, wn = (w >> 1) * 64;
    int kq = lane >> 4, lr = lane & 15;

    f32x4 acc[4][4] = {};

    for (int k0 = 0; k0 < 256; k0 += 32) {
        __syncthreads();
#pragma unroll
        for (int i = 0; i < 2; i++) {
            int c = (i * 4 + w) * 64 + lane;
            int m = c & 127, kqq = c >> 7;
            int row = row0 + m; if (row >= M) row = M - 1;   // clamp: valid addr
            gl2lds16(&A[(long long)row * 256 + k0 + kqq * 8],
                     &ldsA[(i * 4 + w) * 512]);
        }
#pragma unroll
        for (int i = 0; i < 2; i++) {
            int c = (i * 4 + w) * 64 + lane;
            int n = c & 127, kqq = c >> 7;
            gl2lds16(&BT[(long long)(col0 + n) * 256 + k0 + kqq * 8],
                     &ldsB[(i * 4 + w) * 512]);
        }
        __syncthreads();

        bf16x8 a[4], b[4];
#pragma unroll
        for (int t = 0; t < 4; t++) {
            int m = wm + t * 16 + lr;
            a[t] = *(const bf16x8*)&ldsA[(kq * 128 + m) * 8];
            int n = wn + t * 16 + lr;
            b[t] = *(const bf16x8*)&ldsB[(kq * 128 + n) * 8];
        }
#pragma unroll
        for (int mt = 0; mt < 4; mt++)
#pragma unroll
            for (int nt = 0; nt < 4; nt++)
                acc[mt][nt] = __builtin_amdgcn_mfma_f32_16x16x32_bf16(
                    a[mt], b[nt], acc[mt][nt], 0, 0, 0);
    }

    // epilogue: C/D layout col=lane&15, row=(lane>>4)*4+reg  [m89-verified]
#pragma unroll
    for (int mt = 0; mt < 4; mt++) {
#pragma unroll
        for (int nt = 0; nt < 4; nt++) {
            int col = col0 + wn + nt * 16 + lr;
            int rowb = row0 + wm + mt * 16 + kq * 4;
#pragma unroll
            for (int r2 = 0; r2 < 4; r2++) {
                int row = rowb + r2;
                if (row < M) C[(long long)row * 256 + col] = f2bf(acc[mt][nt][r2]);
            }
        }
    }
}

// ---------------- 2-dst-per-wave CSR aggregation core ----------------------
// Wave = two 32-lane groups, each owns one dst row; 8 features/lane (uint4).
// One load instruction moves 2 rows (1KB). 8-deep batch per group.
// Returns acc[8]; d is this group's dst (clamped to valid), gvalid = d < N.
__device__ __forceinline__ void agg_rows2(
        const unsigned short* __restrict__ h,
        const int* __restrict__ srcs, const float* __restrict__ nrm,
        const int* __restrict__ starts, int d, int f0, float dd, float* acc) {
    int lane = threadIdx.x & 63;
    int lr = lane & 31;
    int e0 = starts[d], e1 = starts[d + 1];
    int cnt = e1 - e0;
    int cpre = cnt < 32 ? cnt : 32;

#pragma unroll
    for (int t = 0; t < 8; t++) acc[t] = 0.0f;
    {   // self-loop (also warms L1 with row d for masked slots)
        uint4 v = *(const uint4*)&h[((long long)d << 8) + f0];
        fma8(v, dd, acc);
    }
    int sv = d; float nv = 0.0f;
    if (lr < cpre) { sv = srcs[e0 + lr]; nv = nrm[e0 + lr]; }

    // wave-uniform batch count (max of the two groups)
    int cother = __shfl(cpre, lane ^ 32);
    int cmax = cpre > cother ? cpre : cother;

    for (int base = 0; base < cmax; base += 8) {
        uint4 vv[8]; float nn[8];
#pragma unroll
        for (int t = 0; t < 8; t++) {
            int j = base + t;                        // < 32 always
            int idx = (lane & 32) | j;               // own group's lane j
            int s = __shfl(sv, idx);
            float n = __shfl(nv, idx);
            if (j >= cpre) { s = d; n = 0.0f; }      // group-uniform mask
            nn[t] = n;
            vv[t] = *(const uint4*)&h[((long long)s << 8) + f0];
        }
#pragma unroll
        for (int t = 0; t < 8; t++) fma8(vv[t], nn[t], acc);
    }
    for (int e = e0 + 32; e < e1; e++) {             // rare: degree > 32
        int s0 = srcs[e];
        float n0 = nrm[e];
        uint4 v0 = *(const uint4*)&h[((long long)s0 << 8) + f0];
        fma8(v0, n0, acc);
    }
}

// out = relu( dinv[d]*( h[d]*dinv[d] + sum_s h[s]*dinv[s] ) + bias )
__global__ __launch_bounds__(256) void k_gather_bf16(
        const unsigned short* __restrict__ h,   // bf16 [N][256]
        const int* __restrict__ srcs, const float* __restrict__ nrm,
        const int* __restrict__ starts,
        const float* __restrict__ dinv, const float* __restrict__ bias,
        unsigned short* __restrict__ out, int N, int H) {
    int tid = threadIdx.x;
    int lane = tid & 63;
    int g = (lane >> 5);
    int lr = lane & 31;
    int d = blockIdx.x * 8 + (tid >> 6) * 2 + g;
    int gvalid = (d < N);
    if (d >= N) d = N - 1;                  // keep lanes alive (shfl sources)
    int f0 = lr * 8;
    float dd = dinv[d];

    float acc[8];
    agg_rows2(h, srcs, nrm, starts, d, f0, dd, acc);

    unsigned short o[8];
#pragma unroll
    for (int t = 0; t < 8; t++) {
        int f = f0 + t;
        float bb = (f < H) ? bias[f] : 0.0f;
        float v = fmaxf(acc[t] * dd + bb, 0.0f);   // relu; pad cols stay 0
        o[t] = f2bf(v);
    }
    if (gvalid) {
        uint4 ov;
        ov.x = (unsigned)o[0] | ((unsigned)o[1] << 16);
        ov.y = (unsigned)o[2] | ((unsigned)o[3] << 16);
        ov.z = (unsigned)o[4] | ((unsigned)o[5] << 16);
        ov.w = (unsigned)o[6] | ((unsigned)o[7] << 16);
        *(uint4*)&out[((long long)d << 8) + f0] = ov;
    }
}

// ---------------- layer-4: gather + fused log_softmax ----------------------
__global__ __launch_bounds__(256) void k_gather_lsm(
        const unsigned short* __restrict__ h,   // bf16 [N][256]
        const int* __restrict__ srcs, const float* __restrict__ nrm,
        const int* __restrict__ starts,
        const float* __restrict__ dinv, const float* __restrict__ bias,
        float* __restrict__ out, int N, int H) {
    int tid = threadIdx.x;
    int lane = tid & 63;
    int g = (lane >> 5);
    int lr = lane & 31;
    int d = blockIdx.x * 8 + (tid >> 6) * 2 + g;
    int gvalid = (d < N);
    if (d >= N) d = N - 1;
    int f0 = lr * 8;
    float dd = dinv[d];

    float acc[8];
    agg_rows2(h, srcs, nrm, starts, d, f0, dd, acc);

    float v[8];
    float m = -INFINITY;
#pragma unroll
    for (int t = 0; t < 8; t++) {
        int f = f0 + t;
        float bb = (f < H) ? bias[f] : 0.0f;
        v[t] = acc[t] * dd + bb;
        if (f < H) m = fmaxf(m, v[t]);
    }
#pragma unroll
    for (int off = 16; off > 0; off >>= 1) m = fmaxf(m, __shfl_xor(m, off));
    float s = 0.0f;
#pragma unroll
    for (int t = 0; t < 8; t++) {
        int f = f0 + t;
        if (f < H) s += __expf(v[t] - m);
    }
#pragma unroll
    for (int off = 16; off > 0; off >>= 1) s += __shfl_xor(s, off);
    float lse = m + logf(s);
    if (gvalid) {
#pragma unroll
        for (int t = 0; t < 8; t++) {
            int f = f0 + t;
            if (f < H) out[(long long)d * H + f] = v[t] - lse;
        }
    }
}

// ---------------------------------------------------------------------------
extern "C" void kernel_launch(void* const* d_in, const int* in_sizes, int n_in,
                              void* d_out, int out_size, void* d_ws, size_t ws_size,
                              hipStream_t stream) {
    const float* x    = (const float*)d_in[0];
    const void*  eidx = d_in[1];
    const float* W[4] = {(const float*)d_in[2], (const float*)d_in[4],
                         (const float*)d_in[6], (const float*)d_in[8]};
    const float* b[4] = {(const float*)d_in[3], (const float*)d_in[5],
                         (const float*)d_in[7], (const float*)d_in[9]};

    const int H   = in_sizes[3];          // 246
    const int E   = in_sizes[1] / 2;      // 320000
    const int FIN = in_sizes[2] / H;      // 256
    const int N   = in_sizes[0] / FIN;    // 50000

    auto align = [](size_t v) { return (v + 255) / 256 * 256; };
    char* ws = (char*)d_ws;
    size_t off = 0;
    int* flag = (int*)(ws + off);             off += 256;
    float* dinv = (float*)(ws + off);         off += align((size_t)N * 4);
    int* counts = (int*)(ws + off);           off += align((size_t)N * 4);
    int* starts = (int*)(ws + off);           off += align((size_t)(N + 1) * 4);
    int* srcs = (int*)(ws + off);             off += align((size_t)E * 4);
    float* nrm = (float*)(ws + off);          off += align((size_t)E * 4);
    int nb2 = (N + 1023) / 1024;
    int* bsum = (int*)(ws + off);             off += align((size_t)(nb2 + 1) * 4);
    int* boffs = (int*)(ws + off);            off += align((size_t)(nb2 + 1) * 4);
    unsigned short* Wt[4];
    for (int l = 0; l < 4; l++) {
        Wt[l] = (unsigned short*)(ws + off);  off += 256 * 256 * 2;
    }
    size_t actB = align((size_t)N * 256 * 2);
    unsigned short* A0 = (unsigned short*)(ws + off);  off += actB;
    unsigned short* A1 = (unsigned short*)(ws + off);  off += actB;
    unsigned short* Cb = (unsigned short*)(ws + off);  off += actB;

    int eb = (E + 255) / 256;

    // --- edge dtype detection (+ counts zeroing) ---
    k_flag_init<<<1, 64, 0, stream>>>(flag);
    k_flag_check<<<512, 256, 0, stream>>>((const long long*)eidx, E, (long long)N,
                                          flag, counts, N);

    // --- CSR build ---
    k_count<<<eb, 256, 0, stream>>>(eidx, flag, counts, E);
    k_dinv_bsum<<<nb2, 256, 0, stream>>>(counts, dinv, bsum, N);
    k_scan<<<1, 1024, 0, stream>>>(bsum, boffs, nb2);
    k_scan_final<<<nb2, 256, 0, stream>>>(counts, boffs, starts, N);
    k_fill<<<eb, 256, 0, stream>>>(eidx, flag, counts, srcs, nrm, dinv, E);

    // --- weight + input conversion ---
    k_cvt_w4<<<dim3(256, 4), 256, 0, stream>>>(W[0], W[1], W[2], W[3],
                                               Wt[0], Wt[1], Wt[2], Wt[3],
                                               FIN, H, H);
    k_cvt_x<<<1024, 256, 0, stream>>>(x, A0, (long long)N * FIN / 4);

    int ggrid = 2 * ((N + 127) / 128);
    int gb = (N + 7) / 8;

    // --- layer 1 ---
    k_gemm_mfma<<<ggrid, 256, 0, stream>>>(A0, Wt[0], Cb, N);
    k_gather_bf16<<<gb, 256, 0, stream>>>(Cb, srcs, nrm, starts, dinv, b[0], A1, N, H);
    // --- layer 2 ---
    k_gemm_mfma<<<ggrid, 256, 0, stream>>>(A1, Wt[1], Cb, N);
    k_gather_bf16<<<gb, 256, 0, stream>>>(Cb, srcs, nrm, starts, dinv, b[1], A0, N, H);
    // --- layer 3 ---
    k_gemm_mfma<<<ggrid, 256, 0, stream>>>(A0, Wt[2], Cb, N);
    k_gather_bf16<<<gb, 256, 0, stream>>>(Cb, srcs, nrm, starts, dinv, b[2], A1, N, H);
    // --- layer 4 (fused log_softmax) ---
    k_gemm_mfma<<<ggrid, 256, 0, stream>>>(A1, Wt[3], Cb, N);
    k_gather_lsm<<<gb, 256, 0, stream>>>(Cb, srcs, nrm, starts, dinv, b[3],
                                         (float*)d_out, N, H);
}

// Round 9
// 411.053 us; speedup vs baseline: 1.1516x; 1.1068x over previous
//
#include <hip/hip_runtime.h>
#include <cstdint>
#include <cstddef>

// ---------------------------------------------------------------------------
// 4-layer GCN. Round 19: best-known composition.
// Gather = r12-proven shape verbatim (64-lane/dst, uint2/lane, 8-deep batch,
// per-edge nrm[]; 50.2us / 2.74 TB/s measured). GEMM = XCD-chunked 128x128
// MFMA (r12). Preproc = r16 merged kernels (~11us). r13-r18 fusion/width
// experiments all regressed and are reverted.
// ---------------------------------------------------------------------------

typedef __bf16 bf16x8 __attribute__((ext_vector_type(8)));
typedef float f32x4 __attribute__((ext_vector_type(4)));

__device__ __forceinline__ unsigned short f2bf(float v) {   // RNE
    union { float f; unsigned u; } x; x.f = v;
    unsigned r = x.u + 0x7fff + ((x.u >> 16) & 1);
    return (unsigned short)(r >> 16);
}
__device__ __forceinline__ float bf2f(unsigned short h) {
    union { unsigned u; float f; } x; x.u = (unsigned)h << 16; return x.f;
}

// async global->LDS, 16B per lane; lds base must be wave-uniform
__device__ __forceinline__ void gl2lds16(const void* g, void* l) {
    __builtin_amdgcn_global_load_lds(
        (const __attribute__((address_space(1))) unsigned int*)g,
        (__attribute__((address_space(3))) unsigned int*)l, 16, 0, 0);
}

// acc[0..3] += bf16x4(v) * n
__device__ __forceinline__ void fma4(const uint2 v, float n, float* acc) {
    acc[0] += bf2f((unsigned short)(v.x & 0xffff)) * n;
    acc[1] += bf2f((unsigned short)(v.x >> 16)) * n;
    acc[2] += bf2f((unsigned short)(v.y & 0xffff)) * n;
    acc[3] += bf2f((unsigned short)(v.y >> 16)) * n;
}

// ---------------- edge-index dtype detection + counts zero -----------------
__global__ void k_flag_init(int* flag) {
    if (blockIdx.x == 0 && threadIdx.x == 0) *flag = 1;
}

__global__ void k_flag_check(const long long* __restrict__ p, int E, long long N,
                             int* flag, int* __restrict__ counts, int Ncnt) {
    long long i = (long long)blockIdx.x * blockDim.x + threadIdx.x;
    long long stride = (long long)gridDim.x * blockDim.x;
    for (long long j = i; j < Ncnt; j += stride) counts[j] = 0;   // fused zero
    for (; i < E; i += stride) {
        long long v = p[i];
        if (v < 0 || v >= N) *flag = 0;
    }
}

__device__ __forceinline__ void load_edge(const void* eidx, int fl, int E, int i,
                                          int& s, int& d) {
    if (fl) {
        s = (int)((const long long*)eidx)[i];
        d = (int)((const long long*)eidx)[E + i];
    } else {
        s = ((const int*)eidx)[i];
        d = ((const int*)eidx)[E + i];
    }
}

// ---------------- CSR build -------------------------------------------------
__global__ void k_count(const void* __restrict__ eidx, const int* __restrict__ flag,
                        int* __restrict__ counts, int E) {
    int i = blockIdx.x * blockDim.x + threadIdx.x;
    if (i >= E) return;
    int s, d;
    load_edge(eidx, *flag, E, i, s, d);
    atomicAdd(&counts[d], 1);
}

// dinv + per-1024-chunk sums, merged (256 threads, 4 elems/thread)
__global__ __launch_bounds__(256) void k_dinv_bsum(
        const int* __restrict__ counts, float* __restrict__ dinv,
        int* __restrict__ bsum, int N) {
    __shared__ int ws[4];
    int tid = threadIdx.x, lane = tid & 63, wid = tid >> 6;
    int base = blockIdx.x * 1024 + tid * 4;
    int v[4];
#pragma unroll
    for (int t = 0; t < 4; t++) {
        int i = base + t;
        v[t] = (i < N) ? counts[i] : 0;
        if (i < N) dinv[i] = rsqrtf((float)v[t] + 1.0f);
    }
    int s = v[0] + v[1] + v[2] + v[3];
#pragma unroll
    for (int off = 32; off > 0; off >>= 1) s += __shfl_xor(s, off);
    if (lane == 0) ws[wid] = s;
    __syncthreads();
    if (tid == 0) bsum[blockIdx.x] = ws[0] + ws[1] + ws[2] + ws[3];
}

// small single-block exclusive scan (block sums; n is small)
__global__ __launch_bounds__(1024) void k_scan(const int* __restrict__ counts,
                                               int* __restrict__ starts, int N) {
    __shared__ int wsum[16];
    __shared__ int wscan[16];
    __shared__ int s_carry;
    int tid = threadIdx.x;
    int lane = tid & 63, wid = tid >> 6;
    if (tid == 0) s_carry = 0;
    __syncthreads();
    for (int base = 0; base < N; base += 1024) {
        int i = base + tid;
        int v = (i < N) ? counts[i] : 0;
        int incl = v;
#pragma unroll
        for (int off = 1; off < 64; off <<= 1) {
            int t = __shfl_up(incl, off);
            if (lane >= off) incl += t;
        }
        if (lane == 63) wsum[wid] = incl;
        __syncthreads();
        if (wid == 0 && lane < 16) {
            int w = wsum[lane];
#pragma unroll
            for (int off = 1; off < 16; off <<= 1) {
                int t = __shfl_up(w, off);
                if (lane >= off) w += t;
            }
            wscan[lane] = w;
        }
        __syncthreads();
        int woff = (wid > 0) ? wscan[wid - 1] : 0;
        int excl = s_carry + woff + incl - v;
        if (i < N) starts[i] = excl;
        int total = wscan[15];
        __syncthreads();
        if (tid == 0) s_carry += total;
        __syncthreads();
    }
    if (tid == 0) starts[N] = s_carry;
}

// final: per-1024-chunk exclusive scan + block offset; also writes cursor copy
__global__ __launch_bounds__(256) void k_scan_final(
        int* __restrict__ counts, const int* __restrict__ boffs,
        int* __restrict__ starts, int N) {
    __shared__ int ws[4];
    int tid = threadIdx.x, lane = tid & 63, wid = tid >> 6;
    int base = blockIdx.x * 1024 + tid * 4;
    int v[4];
#pragma unroll
    for (int t = 0; t < 4; t++) {
        int i = base + t;
        v[t] = (i < N) ? counts[i] : 0;
    }
    int tsum = v[0] + v[1] + v[2] + v[3];
    int incl = tsum;
#pragma unroll
    for (int off = 1; off < 64; off <<= 1) {
        int t = __shfl_up(incl, off);
        if (lane >= off) incl += t;
    }
    if (lane == 63) ws[wid] = incl;
    __syncthreads();
    int woff = 0;
#pragma unroll
    for (int w = 0; w < 4; w++)
        if (w < wid) woff += ws[w];
    int run = boffs[blockIdx.x] + woff + incl - tsum;
#pragma unroll
    for (int t = 0; t < 4; t++) {
        int i = base + t;
        if (i < N) { starts[i] = run; counts[i] = run; }   // counts = cursor
        run += v[t];
    }
    if (blockIdx.x == 0 && tid == 0) starts[N] = boffs[gridDim.x];
}

// fill CSR; also precompute per-edge norm = dinv[src]
__global__ void k_fill(const void* __restrict__ eidx, const int* __restrict__ flag,
                       int* __restrict__ cursor, int* __restrict__ srcs,
                       float* __restrict__ nrm, const float* __restrict__ dinv,
                       int E) {
    int i = blockIdx.x * blockDim.x + threadIdx.x;
    if (i >= E) return;
    int s, d;
    load_edge(eidx, *flag, E, i, s, d);
    int pos = atomicAdd(&cursor[d], 1);
    srcs[pos] = s;
    nrm[pos] = dinv[s];
}

// ---------------- conversions ----------------------------------------------
__global__ void k_cvt_x(const float* __restrict__ x, unsigned short* __restrict__ o,
                        long long n4) {
    long long i = (long long)blockIdx.x * blockDim.x + threadIdx.x;
    long long stride = (long long)gridDim.x * blockDim.x;
    for (; i < n4; i += stride) {
        float4 v = ((const float4*)x)[i];
        unsigned a = (unsigned)f2bf(v.x) | ((unsigned)f2bf(v.y) << 16);
        unsigned b = (unsigned)f2bf(v.z) | ((unsigned)f2bf(v.w) << 16);
        ((uint2*)o)[i] = make_uint2(a, b);
    }
}

// all 4 weights in one launch: W [K][H] fp32 -> transposed padded [256][256]
__global__ void k_cvt_w4(const float* __restrict__ W0, const float* __restrict__ W1,
                         const float* __restrict__ W2, const float* __restrict__ W3,
                         unsigned short* __restrict__ T0, unsigned short* __restrict__ T1,
                         unsigned short* __restrict__ T2, unsigned short* __restrict__ T3,
                         int K0, int K123, int H) {
    int l = blockIdx.y;
    const float* W = (l == 0) ? W0 : (l == 1) ? W1 : (l == 2) ? W2 : W3;
    unsigned short* T = (l == 0) ? T0 : (l == 1) ? T1 : (l == 2) ? T2 : T3;
    int K = (l == 0) ? K0 : K123;
    int idx = blockIdx.x * blockDim.x + threadIdx.x;
    if (idx >= 256 * 256) return;
    int k = idx & 255, n = idx >> 8;
    float v = (k < K && n < H) ? W[k * H + n] : 0.0f;
    T[n * 256 + k] = f2bf(v);
}

// ---------------- single-pass bf16 MFMA GEMM -------------------------------
// C[M][256] = A[M][256] @ W[256][256]; A plain bf16, W transposed bf16.
// 128x128 tile, 4 waves, 4x4 grid of 16x16x32 MFMA; XCD-chunked 1-D grid.
__global__ __launch_bounds__(256) void k_gemm_mfma(
        const unsigned short* __restrict__ A,
        const unsigned short* __restrict__ BT,
        unsigned short* __restrict__ C, int M) {
    __shared__ unsigned short ldsA[4 * 128 * 8];    // chunk c = kq*128+m
    __shared__ unsigned short ldsB[4 * 128 * 8];    // chunk c = kq*128+n

    // xcd-chunked bijective remap
    int g = blockIdx.x, nwg = gridDim.x;
    int q = nwg >> 3, r = nwg & 7;
    int xcd = g & 7, slot = g >> 3;
    int work = (xcd < r) ? xcd * (q + 1) + slot
                         : r * (q + 1) + (xcd - r) * q + slot;
    int col0 = (work & 1) * 128;
    int row0 = (work >> 1) * 128;

    int tid = threadIdx.x;
    int lane = tid & 63;
    int w = tid >> 6;
    int wm = (w & 1) * 64, wn = (w >> 1) * 64;
    int kq = lane >> 4, lr = lane & 15;

    f32x4 acc[4][4] = {};

    for (int k0 = 0; k0 < 256; k0 += 32) {
        __syncthreads();
#pragma unroll
        for (int i = 0; i < 2; i++) {
            int c = (i * 4 + w) * 64 + lane;
            int m = c & 127, kqq = c >> 7;
            int row = row0 + m; if (row >= M) row = M - 1;   // clamp: valid addr
            gl2lds16(&A[(long long)row * 256 + k0 + kqq * 8],
                     &ldsA[(i * 4 + w) * 512]);
        }
#pragma unroll
        for (int i = 0; i < 2; i++) {
            int c = (i * 4 + w) * 64 + lane;
            int n = c & 127, kqq = c >> 7;
            gl2lds16(&BT[(long long)(col0 + n) * 256 + k0 + kqq * 8],
                     &ldsB[(i * 4 + w) * 512]);
        }
        __syncthreads();

        bf16x8 a[4], b[4];
#pragma unroll
        for (int t = 0; t < 4; t++) {
            int m = wm + t * 16 + lr;
            a[t] = *(const bf16x8*)&ldsA[(kq * 128 + m) * 8];
            int n = wn + t * 16 + lr;
            b[t] = *(const bf16x8*)&ldsB[(kq * 128 + n) * 8];
        }
#pragma unroll
        for (int mt = 0; mt < 4; mt++)
#pragma unroll
            for (int nt = 0; nt < 4; nt++)
                acc[mt][nt] = __builtin_amdgcn_mfma_f32_16x16x32_bf16(
                    a[mt], b[nt], acc[mt][nt], 0, 0, 0);
    }

    // epilogue: C/D layout col=lane&15, row=(lane>>4)*4+reg  [m89-verified]
#pragma unroll
    for (int mt = 0; mt < 4; mt++) {
#pragma unroll
        for (int nt = 0; nt < 4; nt++) {
            int col = col0 + wn + nt * 16 + lr;
            int rowb = row0 + wm + mt * 16 + kq * 4;
#pragma unroll
            for (int r2 = 0; r2 < 4; r2++) {
                int row = rowb + r2;
                if (row < M) C[(long long)row * 256 + col] = f2bf(acc[mt][nt][r2]);
            }
        }
    }
}

// ---------------- wave-per-dst CSR aggregation core (r12-proven) -----------
// 64 lanes = 1 dst row; 4 features/lane (uint2); 8-deep independent batch.
__device__ __forceinline__ void agg_rows(
        const unsigned short* __restrict__ h,
        const int* __restrict__ srcs, const float* __restrict__ nrm,
        const int* __restrict__ starts, int d, int f0, float dd, float* acc) {
    int lane = threadIdx.x & 63;
    int e0 = starts[d], e1 = starts[d + 1];
    int cnt = e1 - e0;
    int cpre = cnt < 64 ? cnt : 64;

    acc[0] = acc[1] = acc[2] = acc[3] = 0.0f;
    {   // self-loop (also warms L1 with row d for masked slots)
        uint2 v = *(const uint2*)&h[((long long)d << 8) + f0];
        fma4(v, dd, acc);
    }
    int sv = 0; float nv = 0.0f;
    if (lane < cpre) { sv = srcs[e0 + lane]; nv = nrm[e0 + lane]; }

    for (int base = 0; base < cpre; base += 8) {
        uint2 vv[8]; float nn[8];
#pragma unroll
        for (int t = 0; t < 8; t++) {
            int j = base + t;                    // <= 63 always
            int s = __shfl(sv, j);
            float n = __shfl(nv, j);
            if (j >= cpre) { s = d; n = 0.0f; }  // wave-uniform mask
            nn[t] = n;
            vv[t] = *(const uint2*)&h[((long long)s << 8) + f0];
        }
#pragma unroll
        for (int t = 0; t < 8; t++) fma4(vv[t], nn[t], acc);
    }
    for (int e = e0 + 64; e < e1; e++) {         // rare: degree > 64
        int s0 = srcs[e];
        float n0 = nrm[e];
        uint2 v0 = *(const uint2*)&h[((long long)s0 << 8) + f0];
        fma4(v0, n0, acc);
    }
}

// out = relu( dinv[d]*( h[d]*dinv[d] + sum_s h[s]*dinv[s] ) + bias )
__global__ __launch_bounds__(256) void k_gather_bf16(
        const unsigned short* __restrict__ h,   // bf16 [N][256]
        const int* __restrict__ srcs, const float* __restrict__ nrm,
        const int* __restrict__ starts,
        const float* __restrict__ dinv, const float* __restrict__ bias,
        unsigned short* __restrict__ out, int N, int H) {
    int d = blockIdx.x * 4 + (threadIdx.x >> 6);
    if (d >= N) return;
    int lane = threadIdx.x & 63;
    int f0 = lane * 4;
    float dd = dinv[d];

    float acc[4];
    agg_rows(h, srcs, nrm, starts, d, f0, dd, acc);

    unsigned short o[4];
#pragma unroll
    for (int t = 0; t < 4; t++) {
        int f = f0 + t;
        float bb = (f < H) ? bias[f] : 0.0f;
        float v = fmaxf(acc[t] * dd + bb, 0.0f);   // relu; pad cols stay 0
        o[t] = f2bf(v);
    }
    unsigned o01 = (unsigned)o[0] | ((unsigned)o[1] << 16);
    unsigned o23 = (unsigned)o[2] | ((unsigned)o[3] << 16);
    *(uint2*)&out[((long long)d << 8) + f0] = make_uint2(o01, o23);
}

// ---------------- layer-4: gather + fused log_softmax ----------------------
__global__ __launch_bounds__(256) void k_gather_lsm(
        const unsigned short* __restrict__ h,   // bf16 [N][256]
        const int* __restrict__ srcs, const float* __restrict__ nrm,
        const int* __restrict__ starts,
        const float* __restrict__ dinv, const float* __restrict__ bias,
        float* __restrict__ out, int N, int H) {
    int d = blockIdx.x * 4 + (threadIdx.x >> 6);
    if (d >= N) return;
    int lane = threadIdx.x & 63;
    int f0 = lane * 4;
    float dd = dinv[d];

    float acc[4];
    agg_rows(h, srcs, nrm, starts, d, f0, dd, acc);

    float v[4];
    float m = -INFINITY;
#pragma unroll
    for (int t = 0; t < 4; t++) {
        int f = f0 + t;
        float bb = (f < H) ? bias[f] : 0.0f;
        v[t] = acc[t] * dd + bb;
        if (f < H) m = fmaxf(m, v[t]);
    }
#pragma unroll
    for (int off = 32; off > 0; off >>= 1) m = fmaxf(m, __shfl_xor(m, off));
    float s = 0.0f;
#pragma unroll
    for (int t = 0; t < 4; t++) {
        int f = f0 + t;
        if (f < H) s += __expf(v[t] - m);
    }
#pragma unroll
    for (int off = 32; off > 0; off >>= 1) s += __shfl_xor(s, off);
    float lse = m + logf(s);
#pragma unroll
    for (int t = 0; t < 4; t++) {
        int f = f0 + t;
        if (f < H) out[(long long)d * H + f] = v[t] - lse;
    }
}

// ---------------------------------------------------------------------------
extern "C" void kernel_launch(void* const* d_in, const int* in_sizes, int n_in,
                              void* d_out, int out_size, void* d_ws, size_t ws_size,
                              hipStream_t stream) {
    const float* x    = (const float*)d_in[0];
    const void*  eidx = d_in[1];
    const float* W[4] = {(const float*)d_in[2], (const float*)d_in[4],
                         (const float*)d_in[6], (const float*)d_in[8]};
    const float* b[4] = {(const float*)d_in[3], (const float*)d_in[5],
                         (const float*)d_in[7], (const float*)d_in[9]};

    const int H   = in_sizes[3];          // 246
    const int E   = in_sizes[1] / 2;      // 320000
    const int FIN = in_sizes[2] / H;      // 256
    const int N   = in_sizes[0] / FIN;    // 50000

    auto align = [](size_t v) { return (v + 255) / 256 * 256; };
    char* ws = (char*)d_ws;
    size_t off = 0;
    int* flag = (int*)(ws + off);             off += 256;
    float* dinv = (float*)(ws + off);         off += align((size_t)N * 4);
    int* counts = (int*)(ws + off);           off += align((size_t)N * 4);
    int* starts = (int*)(ws + off);           off += align((size_t)(N + 1) * 4);
    int* srcs = (int*)(ws + off);             off += align((size_t)E * 4);
    float* nrm = (float*)(ws + off);          off += align((size_t)E * 4);
    int nb2 = (N + 1023) / 1024;
    int* bsum = (int*)(ws + off);             off += align((size_t)(nb2 + 1) * 4);
    int* boffs = (int*)(ws + off);            off += align((size_t)(nb2 + 1) * 4);
    unsigned short* Wt[4];
    for (int l = 0; l < 4; l++) {
        Wt[l] = (unsigned short*)(ws + off);  off += 256 * 256 * 2;
    }
    size_t actB = align((size_t)N * 256 * 2);
    unsigned short* A0 = (unsigned short*)(ws + off);  off += actB;
    unsigned short* A1 = (unsigned short*)(ws + off);  off += actB;
    unsigned short* Cb = (unsigned short*)(ws + off);  off += actB;

    int eb = (E + 255) / 256;

    // --- edge dtype detection (+ counts zeroing) ---
    k_flag_init<<<1, 64, 0, stream>>>(flag);
    k_flag_check<<<512, 256, 0, stream>>>((const long long*)eidx, E, (long long)N,
                                          flag, counts, N);

    // --- CSR build ---
    k_count<<<eb, 256, 0, stream>>>(eidx, flag, counts, E);
    k_dinv_bsum<<<nb2, 256, 0, stream>>>(counts, dinv, bsum, N);
    k_scan<<<1, 1024, 0, stream>>>(bsum, boffs, nb2);
    k_scan_final<<<nb2, 256, 0, stream>>>(counts, boffs, starts, N);
    k_fill<<<eb, 256, 0, stream>>>(eidx, flag, counts, srcs, nrm, dinv, E);

    // --- weight + input conversion ---
    k_cvt_w4<<<dim3(256, 4), 256, 0, stream>>>(W[0], W[1], W[2], W[3],
                                               Wt[0], Wt[1], Wt[2], Wt[3],
                                               FIN, H, H);
    k_cvt_x<<<1024, 256, 0, stream>>>(x, A0, (long long)N * FIN / 4);

    int ggrid = 2 * ((N + 127) / 128);
    int gb = (N + 3) / 4;

    // --- layer 1 ---
    k_gemm_mfma<<<ggrid, 256, 0, stream>>>(A0, Wt[0], Cb, N);
    k_gather_bf16<<<gb, 256, 0, stream>>>(Cb, srcs, nrm, starts, dinv, b[0], A1, N, H);
    // --- layer 2 ---
    k_gemm_mfma<<<ggrid, 256, 0, stream>>>(A1, Wt[1], Cb, N);
    k_gather_bf16<<<gb, 256, 0, stream>>>(Cb, srcs, nrm, starts, dinv, b[1], A0, N, H);
    // --- layer 3 ---
    k_gemm_mfma<<<ggrid, 256, 0, stream>>>(A0, Wt[2], Cb, N);
    k_gather_bf16<<<gb, 256, 0, stream>>>(Cb, srcs, nrm, starts, dinv, b[2], A1, N, H);
    // --- layer 4 (fused log_softmax) ---
    k_gemm_mfma<<<ggrid, 256, 0, stream>>>(A1, Wt[3], Cb, N);
    k_gather_lsm<<<gb, 256, 0, stream>>>(Cb, srcs, nrm, starts, dinv, b[3],
                                         (float*)d_out, N, H);
}